// Round 12
// baseline (1113.615 us; speedup 1.0000x reference)
//
#include <hip/hip_runtime.h>

typedef __attribute__((ext_vector_type(4))) float f32x4;
typedef __attribute__((ext_vector_type(8))) __bf16 bf16x8;
typedef unsigned short ushort_t;
typedef unsigned int uint_t;
typedef __attribute__((ext_vector_type(4))) uint_t u32x4;

// ---------- bf16 helpers (manual, RNE) ----------
__device__ __forceinline__ float bf2f(ushort_t u) {
  union { uint_t i; float f; } v; v.i = ((uint_t)u) << 16; return v.f;
}
__device__ __forceinline__ ushort_t f2bf(float f) {
  union { float f; uint_t i; } v; v.f = f;
  uint_t x = v.i;
  return (ushort_t)((x + 0x7fffu + ((x >> 16) & 1u)) >> 16);
}

// ---------- async global->LDS, 16B ----------
__device__ __forceinline__ void gload_lds16(const void* g, void* l) {
  __builtin_amdgcn_global_load_lds(
      (const __attribute__((address_space(1))) void*)g,
      (__attribute__((address_space(3))) void*)l, 16, 0, 0);
}

// ---------- 1) fp32 -> bf16 cast (8 elems/thread) ----------
__global__ __launch_bounds__(256) void cast_bf16_kernel(
    const float* __restrict__ in, ushort_t* __restrict__ out, int n8) {
  int i = blockIdx.x * 256 + threadIdx.x;
  if (i >= n8) return;
  float4 a = ((const float4*)in)[i * 2];
  float4 b = ((const float4*)in)[i * 2 + 1];
  ushort4 o0 = make_ushort4(f2bf(a.x), f2bf(a.y), f2bf(a.z), f2bf(a.w));
  ushort4 o1 = make_ushort4(f2bf(b.x), f2bf(b.y), f2bf(b.z), f2bf(b.w));
  ((ushort4*)out)[i * 2] = o0;
  ((ushort4*)out)[i * 2 + 1] = o1;
}

// ---------- 2) transpose + cast: in (R,C) fp32 -> out (C,R) bf16 ----------
__global__ __launch_bounds__(256) void transpose_cast_kernel(
    const float* __restrict__ in, ushort_t* __restrict__ out, int R, int C) {
  __shared__ float tile[32][33];
  int tx = threadIdx.x, ty = threadIdx.y;
  int c0 = blockIdx.x * 32, r0 = blockIdx.y * 32;
#pragma unroll
  for (int i = 0; i < 4; ++i)
    tile[ty + i * 8][tx] = in[(size_t)(r0 + ty + i * 8) * C + c0 + tx];
  __syncthreads();
#pragma unroll
  for (int i = 0; i < 4; ++i)
    out[(size_t)(c0 + ty + i * 8) * R + r0 + tx] = f2bf(tile[tx][ty + i * 8]);
}

// ---------- 3) GEMM: C(M,N) = A(M,K)bf16 * BT(N,K)bf16 ----------
// 128x128 tile, BK=32, 4 waves. 1D grid + XCD-contiguous swizzle (T1).
template <int OUT_BF16>
__global__ __launch_bounds__(256, 2) void gemm_bt_kernel(
    const ushort_t* __restrict__ A, const ushort_t* __restrict__ BT,
    void* __restrict__ Cout, int M, int N, int K, int nx, int cpx) {
  const int lin = blockIdx.x;
  const int swz = (lin & 7) * cpx + (lin >> 3);
  const int bx = swz % nx, by = swz / nx;

  __shared__ ushort_t As[128 * 32];
  __shared__ ushort_t Bs[128 * 32];
  const int tid = threadIdx.x;
  const int lane = tid & 63;
  const int wid = tid >> 6;
  const int wr = wid >> 1, wc = wid & 1;
  const int qr = lane & 15, kg = lane >> 4;
  const size_t arow = (size_t)by * 128;
  const size_t brow = (size_t)bx * 128;

  f32x4 acc[4][4] = {};

  for (int k0 = 0; k0 < K; k0 += 32) {
    __syncthreads();
#pragma unroll
    for (int t = 0; t < 2; ++t) {
      int c = (t * 4 + wid) * 64 + lane;
      int r = c >> 2, kc = (c & 3) * 8;
      gload_lds16(A + (arow + r) * K + k0 + kc, &As[(t * 4 + wid) * 512]);
      gload_lds16(BT + (brow + r) * K + k0 + kc, &Bs[(t * 4 + wid) * 512]);
    }
    __syncthreads();
    bf16x8 af[4], bfr[4];
#pragma unroll
    for (int m = 0; m < 4; ++m)
      af[m] = *(const bf16x8*)&As[(wr * 64 + m * 16 + qr) * 32 + kg * 8];
#pragma unroll
    for (int n = 0; n < 4; ++n)
      bfr[n] = *(const bf16x8*)&Bs[(wc * 64 + n * 16 + qr) * 32 + kg * 8];
#pragma unroll
    for (int m = 0; m < 4; ++m)
#pragma unroll
      for (int n = 0; n < 4; ++n)
        acc[m][n] = __builtin_amdgcn_mfma_f32_16x16x32_bf16(af[m], bfr[n], acc[m][n], 0, 0, 0);
  }

#pragma unroll
  for (int m = 0; m < 4; ++m)
#pragma unroll
    for (int n = 0; n < 4; ++n)
#pragma unroll
      for (int j = 0; j < 4; ++j) {
        size_t row = arow + wr * 64 + m * 16 + kg * 4 + j;
        size_t col = brow + wc * 64 + n * 16 + qr;
        float v = acc[m][n][j];
        if (OUT_BF16) ((ushort_t*)Cout)[row * N + col] = f2bf(v);
        else ((float*)Cout)[row * N + col] = v;
      }
}

// ---------- 4) fused Gemma-RMSNorm + RoPE on q/k rows of qkv, in place ----------
// q rows (idx<16) pre-scaled by 1/sqrt(D)=1/16 (exact in bf16).
__global__ __launch_bounds__(256) void normrope_kernel(
    ushort_t* __restrict__ qkv, const int* __restrict__ positions,
    const float* __restrict__ qw, const float* __restrict__ kw) {
  const int wv = blockIdx.x * 4 + (threadIdx.x >> 6);
  const int lane = threadIdx.x & 63;
  const int t = wv / 18;
  const int idx = wv % 18;
  size_t base;
  const float* w;
  float sc;
  if (idx < 16) { base = (size_t)t * 9216 + idx * 512; w = qw; sc = 0.0625f; }
  else { base = (size_t)t * 9216 + 8192 + (size_t)(idx - 16) * 256; w = kw; sc = 1.0f; }

  ushort4 raw = *(const ushort4*)(qkv + base + lane * 4);
  float x0 = bf2f(raw.x), x1 = bf2f(raw.y), x2 = bf2f(raw.z), x3 = bf2f(raw.w);
  float ss = x0 * x0 + x1 * x1 + x2 * x2 + x3 * x3;
#pragma unroll
  for (int off = 1; off < 64; off <<= 1) ss += __shfl_xor(ss, off);
  float inv = rsqrtf(ss * (1.0f / 256.0f) + 1e-6f);
  const int d0 = lane * 4;
  float xn[4] = { x0 * inv * (1.f + w[d0]), x1 * inv * (1.f + w[d0 + 1]),
                  x2 * inv * (1.f + w[d0 + 2]), x3 * inv * (1.f + w[d0 + 3]) };
  float pn[4];
#pragma unroll
  for (int j = 0; j < 4; ++j) pn[j] = __shfl_xor(xn[j], 8);
  if (lane < 16) {
    const float pos = (float)positions[t];
#pragma unroll
    for (int j = 0; j < 4; ++j) {
      int d = d0 + j;
      int i = d & 31;
      float invf = __expf(-(float)i * 0.28782313662425574f);  // 10000^(-i/32)
      float fr = pos * invf;
      float s, c;
      sincosf(fr, &s, &c);
      xn[j] = (d < 32) ? (xn[j] * c - pn[j] * s) : (xn[j] * c + pn[j] * s);
    }
  }
  ushort4 o = make_ushort4(f2bf(xn[0] * sc), f2bf(xn[1] * sc),
                           f2bf(xn[2] * sc), f2bf(xn[3] * sc));
  *(ushort4*)(qkv + base + lane * 4) = o;
}

// ---------- 4b) V global transpose with interleaved slot order ----------
// VTg[kvh][d][t-block*32 + s] = V[t-block*32 + perm(s)][kvh][d], where
// perm(s) = ((s&1)<<4) + ((s>>3)<<2) + ((s&7)>>1) — the slot->kv map that the
// in-register P pack produces (verified rounds 5/6/8/10/11).
__global__ __launch_bounds__(256) void vtranspose_kernel(
    const ushort_t* __restrict__ qkv, ushort_t* __restrict__ VTg) {
  __shared__ ushort_t tile[32][34];
  const int tx = threadIdx.x, ty = threadIdx.y;
  const int t0 = blockIdx.x * 32, d0 = blockIdx.y * 32, kvh = blockIdx.z;
#pragma unroll
  for (int i = 0; i < 4; ++i) {
    int s = ty + i * 8;
    int kvl = ((s & 1) << 4) + ((s >> 3) << 2) + ((s & 7) >> 1);  // perm(s)
    tile[s][tx] = qkv[(size_t)(t0 + kvl) * 9216 + 8704 + kvh * 256 + d0 + tx];
  }
  __syncthreads();
#pragma unroll
  for (int i = 0; i < 4; ++i)
    VTg[(size_t)kvh * 1048576 + (size_t)(d0 + ty + i * 8) * 4096 + t0 + tx] =
        tile[tx][ty + i * 8];
}

// ---------- softmax for one q-group (swapped-QK layout) ----------
__device__ __forceinline__ bf16x8 softmax_group(
    f32x4 sA, f32x4 sB, int kv0, int qg, bool full,
    float& mr, float& lr, f32x4* o, int kg) {
  float v[8];
#pragma unroll
  for (int j = 0; j < 4; ++j) v[j] = sA[j];
#pragma unroll
  for (int j = 0; j < 4; ++j) v[4 + j] = sB[j];
  if (!full) {
#pragma unroll
    for (int j = 0; j < 4; ++j) {
      if (kv0 + kg * 4 + j > qg) v[j] = -1e30f;
      if (kv0 + 16 + kg * 4 + j > qg) v[4 + j] = -1e30f;
    }
  }
  float tm = v[0];
#pragma unroll
  for (int j = 1; j < 8; ++j) tm = fmaxf(tm, v[j]);
  tm = fmaxf(tm, __shfl_xor(tm, 16));
  tm = fmaxf(tm, __shfl_xor(tm, 32));
  float mref;
  if (__all(tm - mr <= 8.0f)) {
    mref = mr;  // defer-max (T13)
  } else {
    float mnew = fmaxf(mr, tm);
    float corr = __expf(mr - mnew);
    lr *= corr;
    float c0 = __shfl(corr, kg * 4 + 0);
    float c1 = __shfl(corr, kg * 4 + 1);
    float c2 = __shfl(corr, kg * 4 + 2);
    float c3 = __shfl(corr, kg * 4 + 3);
#pragma unroll
    for (int n = 0; n < 16; ++n) {
      o[n][0] *= c0; o[n][1] *= c1; o[n][2] *= c2; o[n][3] *= c3;
    }
    mr = mnew; mref = mnew;
  }
  float p[8];
#pragma unroll
  for (int j = 0; j < 8; ++j) p[j] = __expf(v[j] - mref);
  float ps = 0.f;
#pragma unroll
  for (int j = 0; j < 8; ++j) ps += p[j];
  ps += __shfl_xor(ps, 16);
  ps += __shfl_xor(ps, 32);
  lr += ps;
  union { u32x4 u; bf16x8 b; } pk;
#pragma unroll
  for (int u2 = 0; u2 < 4; ++u2)
    pk.u[u2] = (uint_t)f2bf(p[u2]) | ((uint_t)f2bf(p[4 + u2]) << 16);
  return pk.b;
}

// ---------- one attn pipeline step (tile kt) ----------
// barrier -> issue K(kt+1) -> EARLY-issue V(kt+1) into vfP (covers the whole
// compute phase; round-11 post-mortem: issuing V after compute left the loads
// fully exposed at the next barrier's vmcnt(0) drain) -> compute kt (vfC).
__device__ __forceinline__ void attn_step(
    int kt, int nt, int myq0, int qr, int kg, int wid, int lane, int kvh,
    const ushort_t* __restrict__ qkv, const ushort_t* __restrict__ vtg,
    ushort_t* curKs, ushort_t* nxtKs,
    bf16x8* vfC, bf16x8* vfP,
    const bf16x8* qf, f32x4* o, float& mr, float& lr) {
  const int kv0 = kt * 32;
  __syncthreads();  // K(kt) staged, V(kt) regs landed (aged one compute phase)

  if (kt + 1 < nt) {
    const int kv0n = kv0 + 32;
#pragma unroll
    for (int t = 0; t < 4; ++t) {
      int c = (t * 4 + wid) * 64 + lane;
      int r = c >> 5, dc = c & 31;
      int dcs = dc ^ (r & 7);
      gload_lds16(qkv + (size_t)(kv0n + r) * 9216 + 8192 + kvh * 256 + dcs * 8,
                  &nxtKs[(t * 4 + wid) * 512]);
    }
  }
  __builtin_amdgcn_sched_barrier(0);

  // early V(kt+1) prefetch into the OTHER register buffer
  if ((kt + 1 < nt) && (kv0 + 32 <= myq0 + 15)) {
    const int kv0n = kv0 + 32;
#pragma unroll
    for (int n = 0; n < 16; ++n)
      vfP[n] = *(const bf16x8*)(vtg + (size_t)(n * 16 + qr) * 4096 + kv0n + kg * 8);
  }
  __builtin_amdgcn_sched_barrier(0);

  const bool active = (kv0 <= myq0 + 15);  // wave-uniform causal skip
  if (active) {
    const char* ksb = (const char*)curKs;
    const int kxor = (qr & 7) << 4;
    const int kbase = qr * 512;
    f32x4 s0 = {0.f, 0.f, 0.f, 0.f}, s1 = {0.f, 0.f, 0.f, 0.f};
    __builtin_amdgcn_s_setprio(1);
#pragma unroll
    for (int kd = 0; kd < 8; ++kd) {
      int off = kbase + ((kd * 64 + kg * 16) ^ kxor);
      bf16x8 kf0 = *(const bf16x8*)(ksb + off);
      bf16x8 kf1 = *(const bf16x8*)(ksb + off + 8192);
      s0 = __builtin_amdgcn_mfma_f32_16x16x32_bf16(kf0, qf[kd], s0, 0, 0, 0);
      s1 = __builtin_amdgcn_mfma_f32_16x16x32_bf16(kf1, qf[kd], s1, 0, 0, 0);
    }
    __builtin_amdgcn_s_setprio(0);

    const bool full = (kv0 + 31 <= myq0);
    bf16x8 pf = softmax_group(s0, s1, kv0, myq0 + qr, full, mr, lr, o, kg);

    __builtin_amdgcn_s_setprio(1);
#pragma unroll
    for (int n = 0; n < 16; ++n)
      o[n] = __builtin_amdgcn_mfma_f32_16x16x32_bf16(pf, vfC[n], o[n], 0, 0, 0);
    __builtin_amdgcn_s_setprio(0);
  }
}

// ---------- 5) causal flash attention + sigmoid gate ----------
// QBLK=64 (4 waves x 16 q), KVBLK=32. K LDS-staged (double buffer, single
// barrier/tile). V read DIRECTLY from L2-resident VTg into double-buffered
// register fragments (vfA/vfB), issued right after the barrier so they
// overlap the full compute phase. Loop unrolled x2 for static vf roles
// (nt = 2*qt+2 is always even). LDS 32 KB, VGPR ~190 -> 2 blocks/CU.
__global__ __launch_bounds__(256, 2) void attn_kernel(
    const ushort_t* __restrict__ qkv, const ushort_t* __restrict__ VTg,
    ushort_t* __restrict__ A2) {
  const int id = blockIdx.x;
  const int g8 = id & 255, kk = id >> 8;
  const int x = g8 >> 4;
  const int h = ((g8 & 1) << 3) | ((g8 >> 1) & 7);
  const int qt = (3 - kk) * 16 + ((kk & 1) ? (15 - x) : x);
  const int kvh = g8 & 1;  // == h>>3
  const int tid = threadIdx.x;
  const int lane = tid & 63;
  const int wid = tid >> 6;
  const int qr = lane & 15, kg = lane >> 4;

  __shared__ __align__(16) ushort_t Ks[2][32 * 256];  // [kv][d], chunk-XOR swz

  const int q0 = qt * 64;
  const int myq0 = q0 + wid * 16;
  const ushort_t* vtg = VTg + (size_t)kvh * 1048576;

  bf16x8 qf[8];
#pragma unroll
  for (int kd = 0; kd < 8; ++kd)
    qf[kd] = *(const bf16x8*)(qkv + (size_t)(myq0 + qr) * 9216 + h * 512 +
                              kd * 32 + kg * 8);

  f32x4 o[16] = {};
  float mr = -1e30f, lr = 0.f;

  const int nt = qt * 2 + 2;  // always even

  // prologue: issue K(0) stage; load V(0) fragments into vfA
#pragma unroll
  for (int t = 0; t < 4; ++t) {
    int c = (t * 4 + wid) * 64 + lane;
    int r = c >> 5, dc = c & 31;
    int dcs = dc ^ (r & 7);
    gload_lds16(qkv + (size_t)r * 9216 + 8192 + kvh * 256 + dcs * 8,
                &Ks[0][(t * 4 + wid) * 512]);
  }
  bf16x8 vfA[16], vfB[16];
#pragma unroll
  for (int n = 0; n < 16; ++n)
    vfA[n] = *(const bf16x8*)(vtg + (size_t)(n * 16 + qr) * 4096 + kg * 8);

  for (int kt = 0; kt < nt; kt += 2) {
    attn_step(kt, nt, myq0, qr, kg, wid, lane, kvh, qkv, vtg,
              &Ks[0][0], &Ks[1][0], vfA, vfB, qf, o, mr, lr);
    attn_step(kt + 1, nt, myq0, qr, kg, wid, lane, kvh, qkv, vtg,
              &Ks[1][0], &Ks[0][0], vfB, vfA, qf, o, mr, lr);
  }

  // epilogue: 1/l, sigmoid gate, bf16 store
  float rl[4];
#pragma unroll
  for (int j = 0; j < 4; ++j) rl[j] = 1.0f / __shfl(lr, kg * 4 + j);
#pragma unroll
  for (int n = 0; n < 16; ++n) {
    int d = n * 16 + qr;
#pragma unroll
    for (int j = 0; j < 4; ++j) {
      int t = myq0 + kg * 4 + j;
      float val = o[n][j] * rl[j];
      float g2 = bf2f(qkv[(size_t)t * 9216 + h * 512 + 256 + d]);
      val *= 1.0f / (1.0f + __expf(-g2));
      A2[(size_t)t * 4096 + h * 256 + d] = f2bf(val);
    }
  }
}

// ---------- launch ----------
extern "C" void kernel_launch(void* const* d_in, const int* in_sizes, int n_in,
                              void* d_out, int out_size, void* d_ws, size_t ws_size,
                              hipStream_t stream) {
  const float* hidden = (const float*)d_in[0];
  const int* positions = (const int*)d_in[1];
  const float* w_qkv = (const float*)d_in[2];
  const float* w_o = (const float*)d_in[3];
  const float* q_norm_w = (const float*)d_in[4];
  const float* k_norm_w = (const float*)d_in[5];

  char* ws = (char*)d_ws;
  ushort_t* hb    = (ushort_t*)ws;                          // hidden bf16 (dead after GEMM1)
  ushort_t* VTg   = (ushort_t*)ws;                          // aliases hb: V^T (2,256,4096) bf16
  ushort_t* wqkvT = (ushort_t*)(ws + 16777216);             // w_qkv^T bf16 (9216,2048)
  ushort_t* woT   = (ushort_t*)(ws + 54525952);             // w_o^T bf16 (2048,4096)
  ushort_t* qkvb  = (ushort_t*)(ws + 71303168);             // qkv bf16 (4096,9216)
  ushort_t* A2    = (ushort_t*)(ws + 146800640);            // gated attn bf16 (4096,4096)

  hipLaunchKernelGGL(cast_bf16_kernel, dim3(4096), dim3(256), 0, stream,
                     hidden, hb, 1048576);
  hipLaunchKernelGGL(transpose_cast_kernel, dim3(288, 64), dim3(32, 8), 0, stream,
                     w_qkv, wqkvT, 2048, 9216);
  hipLaunchKernelGGL(transpose_cast_kernel, dim3(64, 128), dim3(32, 8), 0, stream,
                     w_o, woT, 4096, 2048);
  hipLaunchKernelGGL((gemm_bt_kernel<1>), dim3(2304), dim3(256), 0, stream,
                     hb, wqkvT, (void*)qkvb, 4096, 9216, 2048, 72, 288);
  hipLaunchKernelGGL(normrope_kernel, dim3(18432), dim3(256), 0, stream,
                     qkvb, positions, q_norm_w, k_norm_w);
  hipLaunchKernelGGL(vtranspose_kernel, dim3(128, 8, 2), dim3(32, 8), 0, stream,
                     qkvb, VTg);
  hipLaunchKernelGGL(attn_kernel, dim3(1024), dim3(256), 0, stream,
                     qkvb, VTg, A2);
  hipLaunchKernelGGL((gemm_bt_kernel<0>), dim3(512), dim3(256), 0, stream,
                     A2, woT, d_out, 4096, 2048, 4096, 16, 64);
}

// Round 13
// 911.065 us; speedup vs baseline: 1.2223x; 1.2223x over previous
//
#include <hip/hip_runtime.h>

typedef __attribute__((ext_vector_type(4))) float f32x4;
typedef __attribute__((ext_vector_type(8))) __bf16 bf16x8;
typedef unsigned short ushort_t;
typedef unsigned int uint_t;
typedef __attribute__((ext_vector_type(4))) uint_t u32x4;

// ---------- bf16 helpers (manual, RNE) ----------
__device__ __forceinline__ float bf2f(ushort_t u) {
  union { uint_t i; float f; } v; v.i = ((uint_t)u) << 16; return v.f;
}
__device__ __forceinline__ ushort_t f2bf(float f) {
  union { float f; uint_t i; } v; v.f = f;
  uint_t x = v.i;
  return (ushort_t)((x + 0x7fffu + ((x >> 16) & 1u)) >> 16);
}

// ---------- async global->LDS, 16B ----------
__device__ __forceinline__ void gload_lds16(const void* g, void* l) {
  __builtin_amdgcn_global_load_lds(
      (const __attribute__((address_space(1))) void*)g,
      (__attribute__((address_space(3))) void*)l, 16, 0, 0);
}

// ---------- 1) fp32 -> bf16 cast (8 elems/thread) ----------
__global__ __launch_bounds__(256) void cast_bf16_kernel(
    const float* __restrict__ in, ushort_t* __restrict__ out, int n8) {
  int i = blockIdx.x * 256 + threadIdx.x;
  if (i >= n8) return;
  float4 a = ((const float4*)in)[i * 2];
  float4 b = ((const float4*)in)[i * 2 + 1];
  ushort4 o0 = make_ushort4(f2bf(a.x), f2bf(a.y), f2bf(a.z), f2bf(a.w));
  ushort4 o1 = make_ushort4(f2bf(b.x), f2bf(b.y), f2bf(b.z), f2bf(b.w));
  ((ushort4*)out)[i * 2] = o0;
  ((ushort4*)out)[i * 2 + 1] = o1;
}

// ---------- 2) transpose + cast: in (R,C) fp32 -> out (C,R) bf16 ----------
__global__ __launch_bounds__(256) void transpose_cast_kernel(
    const float* __restrict__ in, ushort_t* __restrict__ out, int R, int C) {
  __shared__ float tile[32][33];
  int tx = threadIdx.x, ty = threadIdx.y;
  int c0 = blockIdx.x * 32, r0 = blockIdx.y * 32;
#pragma unroll
  for (int i = 0; i < 4; ++i)
    tile[ty + i * 8][tx] = in[(size_t)(r0 + ty + i * 8) * C + c0 + tx];
  __syncthreads();
#pragma unroll
  for (int i = 0; i < 4; ++i)
    out[(size_t)(c0 + ty + i * 8) * R + r0 + tx] = f2bf(tile[tx][ty + i * 8]);
}

// ---------- 3) GEMM: C(M,N) = A(M,K)bf16 * BT(N,K)bf16 ----------
// 128x128 tile, BK=32, 4 waves. 1D grid + XCD-contiguous swizzle (T1).
template <int OUT_BF16>
__global__ __launch_bounds__(256, 2) void gemm_bt_kernel(
    const ushort_t* __restrict__ A, const ushort_t* __restrict__ BT,
    void* __restrict__ Cout, int M, int N, int K, int nx, int cpx) {
  const int lin = blockIdx.x;
  const int swz = (lin & 7) * cpx + (lin >> 3);
  const int bx = swz % nx, by = swz / nx;

  __shared__ ushort_t As[128 * 32];
  __shared__ ushort_t Bs[128 * 32];
  const int tid = threadIdx.x;
  const int lane = tid & 63;
  const int wid = tid >> 6;
  const int wr = wid >> 1, wc = wid & 1;
  const int qr = lane & 15, kg = lane >> 4;
  const size_t arow = (size_t)by * 128;
  const size_t brow = (size_t)bx * 128;

  f32x4 acc[4][4] = {};

  for (int k0 = 0; k0 < K; k0 += 32) {
    __syncthreads();
#pragma unroll
    for (int t = 0; t < 2; ++t) {
      int c = (t * 4 + wid) * 64 + lane;
      int r = c >> 2, kc = (c & 3) * 8;
      gload_lds16(A + (arow + r) * K + k0 + kc, &As[(t * 4 + wid) * 512]);
      gload_lds16(BT + (brow + r) * K + k0 + kc, &Bs[(t * 4 + wid) * 512]);
    }
    __syncthreads();
    bf16x8 af[4], bfr[4];
#pragma unroll
    for (int m = 0; m < 4; ++m)
      af[m] = *(const bf16x8*)&As[(wr * 64 + m * 16 + qr) * 32 + kg * 8];
#pragma unroll
    for (int n = 0; n < 4; ++n)
      bfr[n] = *(const bf16x8*)&Bs[(wc * 64 + n * 16 + qr) * 32 + kg * 8];
#pragma unroll
    for (int m = 0; m < 4; ++m)
#pragma unroll
      for (int n = 0; n < 4; ++n)
        acc[m][n] = __builtin_amdgcn_mfma_f32_16x16x32_bf16(af[m], bfr[n], acc[m][n], 0, 0, 0);
  }

#pragma unroll
  for (int m = 0; m < 4; ++m)
#pragma unroll
    for (int n = 0; n < 4; ++n)
#pragma unroll
      for (int j = 0; j < 4; ++j) {
        size_t row = arow + wr * 64 + m * 16 + kg * 4 + j;
        size_t col = brow + wc * 64 + n * 16 + qr;
        float v = acc[m][n][j];
        if (OUT_BF16) ((ushort_t*)Cout)[row * N + col] = f2bf(v);
        else ((float*)Cout)[row * N + col] = v;
      }
}

// ---------- 4) fused Gemma-RMSNorm + RoPE on q/k rows of qkv, in place ----------
// q rows (idx<16) pre-scaled by 1/sqrt(D)=1/16 (exact in bf16).
__global__ __launch_bounds__(256) void normrope_kernel(
    ushort_t* __restrict__ qkv, const int* __restrict__ positions,
    const float* __restrict__ qw, const float* __restrict__ kw) {
  const int wv = blockIdx.x * 4 + (threadIdx.x >> 6);
  const int lane = threadIdx.x & 63;
  const int t = wv / 18;
  const int idx = wv % 18;
  size_t base;
  const float* w;
  float sc;
  if (idx < 16) { base = (size_t)t * 9216 + idx * 512; w = qw; sc = 0.0625f; }
  else { base = (size_t)t * 9216 + 8192 + (size_t)(idx - 16) * 256; w = kw; sc = 1.0f; }

  ushort4 raw = *(const ushort4*)(qkv + base + lane * 4);
  float x0 = bf2f(raw.x), x1 = bf2f(raw.y), x2 = bf2f(raw.z), x3 = bf2f(raw.w);
  float ss = x0 * x0 + x1 * x1 + x2 * x2 + x3 * x3;
#pragma unroll
  for (int off = 1; off < 64; off <<= 1) ss += __shfl_xor(ss, off);
  float inv = rsqrtf(ss * (1.0f / 256.0f) + 1e-6f);
  const int d0 = lane * 4;
  float xn[4] = { x0 * inv * (1.f + w[d0]), x1 * inv * (1.f + w[d0 + 1]),
                  x2 * inv * (1.f + w[d0 + 2]), x3 * inv * (1.f + w[d0 + 3]) };
  float pn[4];
#pragma unroll
  for (int j = 0; j < 4; ++j) pn[j] = __shfl_xor(xn[j], 8);
  if (lane < 16) {
    const float pos = (float)positions[t];
#pragma unroll
    for (int j = 0; j < 4; ++j) {
      int d = d0 + j;
      int i = d & 31;
      float invf = __expf(-(float)i * 0.28782313662425574f);  // 10000^(-i/32)
      float fr = pos * invf;
      float s, c;
      sincosf(fr, &s, &c);
      xn[j] = (d < 32) ? (xn[j] * c - pn[j] * s) : (xn[j] * c + pn[j] * s);
    }
  }
  ushort4 o = make_ushort4(f2bf(xn[0] * sc), f2bf(xn[1] * sc),
                           f2bf(xn[2] * sc), f2bf(xn[3] * sc));
  *(ushort4*)(qkv + base + lane * 4) = o;
}

// ---------- 4b) V global transpose with interleaved slot order ----------
// VTg[kvh][d][t-block*32 + s] = V[t-block*32 + perm(s)][kvh][d], where
// perm(s) = ((s&1)<<4) + ((s>>3)<<2) + ((s&7)>>1) — the slot->kv map that the
// in-register P pack produces (verified rounds 5/6/8/10).
__global__ __launch_bounds__(256) void vtranspose_kernel(
    const ushort_t* __restrict__ qkv, ushort_t* __restrict__ VTg) {
  __shared__ ushort_t tile[32][34];
  const int tx = threadIdx.x, ty = threadIdx.y;
  const int t0 = blockIdx.x * 32, d0 = blockIdx.y * 32, kvh = blockIdx.z;
#pragma unroll
  for (int i = 0; i < 4; ++i) {
    int s = ty + i * 8;
    int kvl = ((s & 1) << 4) + ((s >> 3) << 2) + ((s & 7) >> 1);  // perm(s)
    tile[s][tx] = qkv[(size_t)(t0 + kvl) * 9216 + 8704 + kvh * 256 + d0 + tx];
  }
  __syncthreads();
#pragma unroll
  for (int i = 0; i < 4; ++i)
    VTg[(size_t)kvh * 1048576 + (size_t)(d0 + ty + i * 8) * 4096 + t0 + tx] =
        tile[tx][ty + i * 8];
}

// ---------- softmax for one q-group (swapped-QK layout) ----------
// Lane (qr,kg) holds S[q=qg][kv0 + {kg*4+j, 16+kg*4+j}] in sA/sB (pre-scaled
// Q). Returns packed P fragment: dword u = (p[u], p[4+u]) — slot order
// matching perm(s) in VTg. No LDS round-trip.
__device__ __forceinline__ bf16x8 softmax_group(
    f32x4 sA, f32x4 sB, int kv0, int qg, bool full,
    float& mr, float& lr, f32x4* o, int kg) {
  float v[8];
#pragma unroll
  for (int j = 0; j < 4; ++j) v[j] = sA[j];
#pragma unroll
  for (int j = 0; j < 4; ++j) v[4 + j] = sB[j];
  if (!full) {
#pragma unroll
    for (int j = 0; j < 4; ++j) {
      if (kv0 + kg * 4 + j > qg) v[j] = -1e30f;
      if (kv0 + 16 + kg * 4 + j > qg) v[4 + j] = -1e30f;
    }
  }
  float tm = v[0];
#pragma unroll
  for (int j = 1; j < 8; ++j) tm = fmaxf(tm, v[j]);
  tm = fmaxf(tm, __shfl_xor(tm, 16));
  tm = fmaxf(tm, __shfl_xor(tm, 32));
  float mref;
  if (__all(tm - mr <= 8.0f)) {
    mref = mr;  // defer-max (T13)
  } else {
    float mnew = fmaxf(mr, tm);
    float corr = __expf(mr - mnew);
    lr *= corr;
    float c0 = __shfl(corr, kg * 4 + 0);
    float c1 = __shfl(corr, kg * 4 + 1);
    float c2 = __shfl(corr, kg * 4 + 2);
    float c3 = __shfl(corr, kg * 4 + 3);
#pragma unroll
    for (int n = 0; n < 16; ++n) {
      o[n][0] *= c0; o[n][1] *= c1; o[n][2] *= c2; o[n][3] *= c3;
    }
    mr = mnew; mref = mnew;
  }
  float p[8];
#pragma unroll
  for (int j = 0; j < 8; ++j) p[j] = __expf(v[j] - mref);
  float ps = 0.f;
#pragma unroll
  for (int j = 0; j < 8; ++j) ps += p[j];
  ps += __shfl_xor(ps, 16);
  ps += __shfl_xor(ps, 32);
  lr += ps;
  union { u32x4 u; bf16x8 b; } pk;
#pragma unroll
  for (int u2 = 0; u2 < 4; ++u2)
    pk.u[u2] = (uint_t)f2bf(p[u2]) | ((uint_t)f2bf(p[4 + u2]) << 16);
  return pk.b;
}

// ---------- 5) causal flash attention + sigmoid gate ----------
// QBLK=64 (4 waves x 16 q), KVBLK=32. K staged via global_load_lds into a
// double buffer (single barrier/tile). V is read DIRECTLY from L2-resident
// VTg into a SINGLE vf[16] register buffer, with the loads issued at the TOP
// of each phase — BEFORE the K(t+1) gload issue (so the PV wait is a counted
// vmcnt, keeping the K prefetch in flight) and covered by the QK^T+softmax
// compute of the same phase. Rounds 11/12 post-mortem: V-at-end exposed the
// loads at the barrier drain; pointer-passed double-buffers spilled to
// scratch (WRITE_SIZE 596 MB). Fully inline, no pointer-passed reg arrays.
// LDS 32 KB, ~170 VGPR -> 2 blocks/CU under (256,2).
__global__ __launch_bounds__(256, 2) void attn_kernel(
    const ushort_t* __restrict__ qkv, const ushort_t* __restrict__ VTg,
    ushort_t* __restrict__ A2) {
  const int id = blockIdx.x;
  const int g8 = id & 255, kk = id >> 8;
  const int x = g8 >> 4;
  const int h = ((g8 & 1) << 3) | ((g8 >> 1) & 7);
  const int qt = (3 - kk) * 16 + ((kk & 1) ? (15 - x) : x);
  const int kvh = g8 & 1;  // == h>>3
  const int tid = threadIdx.x;
  const int lane = tid & 63;
  const int wid = tid >> 6;
  const int qr = lane & 15, kg = lane >> 4;

  __shared__ __align__(16) ushort_t Ks[2][32 * 256];  // [kv][d], chunk-XOR swz

  const int q0 = qt * 64;
  const int myq0 = q0 + wid * 16;
  // per-lane V row base: vf[n] = vrow[n*16*4096 + kv0]
  const ushort_t* vrow = VTg + (size_t)kvh * 1048576 + (size_t)qr * 4096 + kg * 8;

  bf16x8 qf[8];
#pragma unroll
  for (int kd = 0; kd < 8; ++kd)
    qf[kd] = *(const bf16x8*)(qkv + (size_t)(myq0 + qr) * 9216 + h * 512 +
                              kd * 32 + kg * 8);

  f32x4 o[16] = {};
  float mr = -1e30f, lr = 0.f;

  const int nt = qt * 2 + 2;

  // prologue: issue K(0) stage
#pragma unroll
  for (int t = 0; t < 4; ++t) {
    int c = (t * 4 + wid) * 64 + lane;
    int r = c >> 5, dc = c & 31;
    int dcs = dc ^ (r & 7);
    gload_lds16(qkv + (size_t)r * 9216 + 8192 + kvh * 256 + dcs * 8,
                &Ks[0][(t * 4 + wid) * 512]);
  }

  int buf = 0;
  for (int kt = 0; kt < nt; ++kt) {
    const int kv0 = kt * 32;
    __syncthreads();  // K(kt) staged (loads aged one full compute phase)

    const bool active = (kv0 <= myq0 + 15);  // wave-uniform causal skip

    // ---- V(kt) register loads FIRST (so PV's wait is a counted vmcnt,
    //      not a full drain); covered by the QK^T+softmax below ----
    bf16x8 vf[16];
    if (active) {
#pragma unroll
      for (int n = 0; n < 16; ++n)
        vf[n] = *(const bf16x8*)(vrow + (size_t)n * 65536 + kv0);
    }

    // ---- issue K stage of tile kt+1 into the other buffer ----
    if (kt + 1 < nt) {
      const int kv0n = kv0 + 32;
#pragma unroll
      for (int t = 0; t < 4; ++t) {
        int c = (t * 4 + wid) * 64 + lane;
        int r = c >> 5, dc = c & 31;
        int dcs = dc ^ (r & 7);
        gload_lds16(qkv + (size_t)(kv0n + r) * 9216 + 8192 + kvh * 256 + dcs * 8,
                    &Ks[buf ^ 1][(t * 4 + wid) * 512]);
      }
    }
    __builtin_amdgcn_sched_barrier(0);

    // ---- compute tile kt ----
    if (active) {
      const char* ksb = (const char*)&Ks[buf][0];
      const int kxor = (qr & 7) << 4;
      const int kbase = qr * 512;
      f32x4 s0 = {0.f, 0.f, 0.f, 0.f}, s1 = {0.f, 0.f, 0.f, 0.f};
      __builtin_amdgcn_s_setprio(1);
#pragma unroll
      for (int kd = 0; kd < 8; ++kd) {
        int off = kbase + ((kd * 64 + kg * 16) ^ kxor);
        bf16x8 kf0 = *(const bf16x8*)(ksb + off);
        bf16x8 kf1 = *(const bf16x8*)(ksb + off + 8192);
        s0 = __builtin_amdgcn_mfma_f32_16x16x32_bf16(kf0, qf[kd], s0, 0, 0, 0);
        s1 = __builtin_amdgcn_mfma_f32_16x16x32_bf16(kf1, qf[kd], s1, 0, 0, 0);
      }
      __builtin_amdgcn_s_setprio(0);

      const bool full = (kv0 + 31 <= myq0);
      bf16x8 pf = softmax_group(s0, s1, kv0, myq0 + qr, full, mr, lr, o, kg);

      __builtin_amdgcn_s_setprio(1);
#pragma unroll
      for (int n = 0; n < 16; ++n)
        o[n] = __builtin_amdgcn_mfma_f32_16x16x32_bf16(pf, vf[n], o[n], 0, 0, 0);
      __builtin_amdgcn_s_setprio(0);
    }
    buf ^= 1;
  }

  // epilogue: 1/l, sigmoid gate, bf16 store
  float rl[4];
#pragma unroll
  for (int j = 0; j < 4; ++j) rl[j] = 1.0f / __shfl(lr, kg * 4 + j);
#pragma unroll
  for (int n = 0; n < 16; ++n) {
    int d = n * 16 + qr;
#pragma unroll
    for (int j = 0; j < 4; ++j) {
      int t = myq0 + kg * 4 + j;
      float val = o[n][j] * rl[j];
      float g2 = bf2f(qkv[(size_t)t * 9216 + h * 512 + 256 + d]);
      val *= 1.0f / (1.0f + __expf(-g2));
      A2[(size_t)t * 4096 + h * 256 + d] = f2bf(val);
    }
  }
}

// ---------- launch ----------
extern "C" void kernel_launch(void* const* d_in, const int* in_sizes, int n_in,
                              void* d_out, int out_size, void* d_ws, size_t ws_size,
                              hipStream_t stream) {
  const float* hidden = (const float*)d_in[0];
  const int* positions = (const int*)d_in[1];
  const float* w_qkv = (const float*)d_in[2];
  const float* w_o = (const float*)d_in[3];
  const float* q_norm_w = (const float*)d_in[4];
  const float* k_norm_w = (const float*)d_in[5];

  char* ws = (char*)d_ws;
  ushort_t* hb    = (ushort_t*)ws;                          // hidden bf16 (dead after GEMM1)
  ushort_t* VTg   = (ushort_t*)ws;                          // aliases hb: V^T (2,256,4096) bf16
  ushort_t* wqkvT = (ushort_t*)(ws + 16777216);             // w_qkv^T bf16 (9216,2048)
  ushort_t* woT   = (ushort_t*)(ws + 54525952);             // w_o^T bf16 (2048,4096)
  ushort_t* qkvb  = (ushort_t*)(ws + 71303168);             // qkv bf16 (4096,9216)
  ushort_t* A2    = (ushort_t*)(ws + 146800640);            // gated attn bf16 (4096,4096)

  hipLaunchKernelGGL(cast_bf16_kernel, dim3(4096), dim3(256), 0, stream,
                     hidden, hb, 1048576);
  hipLaunchKernelGGL(transpose_cast_kernel, dim3(288, 64), dim3(32, 8), 0, stream,
                     w_qkv, wqkvT, 2048, 9216);
  hipLaunchKernelGGL(transpose_cast_kernel, dim3(64, 128), dim3(32, 8), 0, stream,
                     w_o, woT, 4096, 2048);
  hipLaunchKernelGGL((gemm_bt_kernel<1>), dim3(2304), dim3(256), 0, stream,
                     hb, wqkvT, (void*)qkvb, 4096, 9216, 2048, 72, 288);
  hipLaunchKernelGGL(normrope_kernel, dim3(18432), dim3(256), 0, stream,
                     qkvb, positions, q_norm_w, k_norm_w);
  hipLaunchKernelGGL(vtranspose_kernel, dim3(128, 8, 2), dim3(32, 8), 0, stream,
                     qkvb, VTg);
  hipLaunchKernelGGL(attn_kernel, dim3(1024), dim3(256), 0, stream,
                     qkvb, VTg, A2);
  hipLaunchKernelGGL((gemm_bt_kernel<0>), dim3(512), dim3(256), 0, stream,
                     A2, woT, d_out, 4096, 2048, 4096, 16, 64);
}

// Round 14
// 645.306 us; speedup vs baseline: 1.7257x; 1.4118x over previous
//
#include <hip/hip_runtime.h>

typedef __attribute__((ext_vector_type(4))) float f32x4;
typedef __attribute__((ext_vector_type(8))) __bf16 bf16x8;
typedef unsigned short ushort_t;
typedef unsigned int uint_t;
typedef __attribute__((ext_vector_type(4))) uint_t u32x4;

// ---------- bf16 helpers (manual, RNE) ----------
__device__ __forceinline__ float bf2f(ushort_t u) {
  union { uint_t i; float f; } v; v.i = ((uint_t)u) << 16; return v.f;
}
__device__ __forceinline__ ushort_t f2bf(float f) {
  union { float f; uint_t i; } v; v.f = f;
  uint_t x = v.i;
  return (ushort_t)((x + 0x7fffu + ((x >> 16) & 1u)) >> 16);
}

// ---------- async global->LDS, 16B ----------
__device__ __forceinline__ void gload_lds16(const void* g, void* l) {
  __builtin_amdgcn_global_load_lds(
      (const __attribute__((address_space(1))) void*)g,
      (__attribute__((address_space(3))) void*)l, 16, 0, 0);
}

// ---------- 1) fp32 -> bf16 cast (8 elems/thread) ----------
__global__ __launch_bounds__(256) void cast_bf16_kernel(
    const float* __restrict__ in, ushort_t* __restrict__ out, int n8) {
  int i = blockIdx.x * 256 + threadIdx.x;
  if (i >= n8) return;
  float4 a = ((const float4*)in)[i * 2];
  float4 b = ((const float4*)in)[i * 2 + 1];
  ushort4 o0 = make_ushort4(f2bf(a.x), f2bf(a.y), f2bf(a.z), f2bf(a.w));
  ushort4 o1 = make_ushort4(f2bf(b.x), f2bf(b.y), f2bf(b.z), f2bf(b.w));
  ((ushort4*)out)[i * 2] = o0;
  ((ushort4*)out)[i * 2 + 1] = o1;
}

// ---------- 2) transpose + cast: in (R,C) fp32 -> out (C,R) bf16 ----------
__global__ __launch_bounds__(256) void transpose_cast_kernel(
    const float* __restrict__ in, ushort_t* __restrict__ out, int R, int C) {
  __shared__ float tile[32][33];
  int tx = threadIdx.x, ty = threadIdx.y;
  int c0 = blockIdx.x * 32, r0 = blockIdx.y * 32;
#pragma unroll
  for (int i = 0; i < 4; ++i)
    tile[ty + i * 8][tx] = in[(size_t)(r0 + ty + i * 8) * C + c0 + tx];
  __syncthreads();
#pragma unroll
  for (int i = 0; i < 4; ++i)
    out[(size_t)(c0 + ty + i * 8) * R + r0 + tx] = f2bf(tile[tx][ty + i * 8]);
}

// ---------- 3) GEMM: C(M,N) = A(M,K)bf16 * BT(N,K)bf16 ----------
// 128x128 tile, BK=32, 4 waves. 1D grid + XCD-contiguous swizzle (T1).
template <int OUT_BF16>
__global__ __launch_bounds__(256, 2) void gemm_bt_kernel(
    const ushort_t* __restrict__ A, const ushort_t* __restrict__ BT,
    void* __restrict__ Cout, int M, int N, int K, int nx, int cpx) {
  const int lin = blockIdx.x;
  const int swz = (lin & 7) * cpx + (lin >> 3);
  const int bx = swz % nx, by = swz / nx;

  __shared__ ushort_t As[128 * 32];
  __shared__ ushort_t Bs[128 * 32];
  const int tid = threadIdx.x;
  const int lane = tid & 63;
  const int wid = tid >> 6;
  const int wr = wid >> 1, wc = wid & 1;
  const int qr = lane & 15, kg = lane >> 4;
  const size_t arow = (size_t)by * 128;
  const size_t brow = (size_t)bx * 128;

  f32x4 acc[4][4] = {};

  for (int k0 = 0; k0 < K; k0 += 32) {
    __syncthreads();
#pragma unroll
    for (int t = 0; t < 2; ++t) {
      int c = (t * 4 + wid) * 64 + lane;
      int r = c >> 2, kc = (c & 3) * 8;
      gload_lds16(A + (arow + r) * K + k0 + kc, &As[(t * 4 + wid) * 512]);
      gload_lds16(BT + (brow + r) * K + k0 + kc, &Bs[(t * 4 + wid) * 512]);
    }
    __syncthreads();
    bf16x8 af[4], bfr[4];
#pragma unroll
    for (int m = 0; m < 4; ++m)
      af[m] = *(const bf16x8*)&As[(wr * 64 + m * 16 + qr) * 32 + kg * 8];
#pragma unroll
    for (int n = 0; n < 4; ++n)
      bfr[n] = *(const bf16x8*)&Bs[(wc * 64 + n * 16 + qr) * 32 + kg * 8];
#pragma unroll
    for (int m = 0; m < 4; ++m)
#pragma unroll
      for (int n = 0; n < 4; ++n)
        acc[m][n] = __builtin_amdgcn_mfma_f32_16x16x32_bf16(af[m], bfr[n], acc[m][n], 0, 0, 0);
  }

#pragma unroll
  for (int m = 0; m < 4; ++m)
#pragma unroll
    for (int n = 0; n < 4; ++n)
#pragma unroll
      for (int j = 0; j < 4; ++j) {
        size_t row = arow + wr * 64 + m * 16 + kg * 4 + j;
        size_t col = brow + wc * 64 + n * 16 + qr;
        float v = acc[m][n][j];
        if (OUT_BF16) ((ushort_t*)Cout)[row * N + col] = f2bf(v);
        else ((float*)Cout)[row * N + col] = v;
      }
}

// ---------- 4) fused Gemma-RMSNorm + RoPE on q/k rows of qkv, in place ----------
// q rows (idx<16) pre-scaled by 1/sqrt(D)=1/16 (exact in bf16).
__global__ __launch_bounds__(256) void normrope_kernel(
    ushort_t* __restrict__ qkv, const int* __restrict__ positions,
    const float* __restrict__ qw, const float* __restrict__ kw) {
  const int wv = blockIdx.x * 4 + (threadIdx.x >> 6);
  const int lane = threadIdx.x & 63;
  const int t = wv / 18;
  const int idx = wv % 18;
  size_t base;
  const float* w;
  float sc;
  if (idx < 16) { base = (size_t)t * 9216 + idx * 512; w = qw; sc = 0.0625f; }
  else { base = (size_t)t * 9216 + 8192 + (size_t)(idx - 16) * 256; w = kw; sc = 1.0f; }

  ushort4 raw = *(const ushort4*)(qkv + base + lane * 4);
  float x0 = bf2f(raw.x), x1 = bf2f(raw.y), x2 = bf2f(raw.z), x3 = bf2f(raw.w);
  float ss = x0 * x0 + x1 * x1 + x2 * x2 + x3 * x3;
#pragma unroll
  for (int off = 1; off < 64; off <<= 1) ss += __shfl_xor(ss, off);
  float inv = rsqrtf(ss * (1.0f / 256.0f) + 1e-6f);
  const int d0 = lane * 4;
  float xn[4] = { x0 * inv * (1.f + w[d0]), x1 * inv * (1.f + w[d0 + 1]),
                  x2 * inv * (1.f + w[d0 + 2]), x3 * inv * (1.f + w[d0 + 3]) };
  float pn[4];
#pragma unroll
  for (int j = 0; j < 4; ++j) pn[j] = __shfl_xor(xn[j], 8);
  if (lane < 16) {
    const float pos = (float)positions[t];
#pragma unroll
    for (int j = 0; j < 4; ++j) {
      int d = d0 + j;
      int i = d & 31;
      float invf = __expf(-(float)i * 0.28782313662425574f);  // 10000^(-i/32)
      float fr = pos * invf;
      float s, c;
      sincosf(fr, &s, &c);
      xn[j] = (d < 32) ? (xn[j] * c - pn[j] * s) : (xn[j] * c + pn[j] * s);
    }
  }
  ushort4 o = make_ushort4(f2bf(xn[0] * sc), f2bf(xn[1] * sc),
                           f2bf(xn[2] * sc), f2bf(xn[3] * sc));
  *(ushort4*)(qkv + base + lane * 4) = o;
}

// ---------- 4b) V global transpose with interleaved slot order ----------
// VTg[kvh][d][t-block*32 + s] = V[t-block*32 + perm(s)][kvh][d], where
// perm(s) = ((s&1)<<4) + ((s>>3)<<2) + ((s&7)>>1) — the slot->kv map that the
// in-register P pack produces (verified rounds 5/6/8/10).
__global__ __launch_bounds__(256) void vtranspose_kernel(
    const ushort_t* __restrict__ qkv, ushort_t* __restrict__ VTg) {
  __shared__ ushort_t tile[32][34];
  const int tx = threadIdx.x, ty = threadIdx.y;
  const int t0 = blockIdx.x * 32, d0 = blockIdx.y * 32, kvh = blockIdx.z;
#pragma unroll
  for (int i = 0; i < 4; ++i) {
    int s = ty + i * 8;
    int kvl = ((s & 1) << 4) + ((s >> 3) << 2) + ((s & 7) >> 1);  // perm(s)
    tile[s][tx] = qkv[(size_t)(t0 + kvl) * 9216 + 8704 + kvh * 256 + d0 + tx];
  }
  __syncthreads();
#pragma unroll
  for (int i = 0; i < 4; ++i)
    VTg[(size_t)kvh * 1048576 + (size_t)(d0 + ty + i * 8) * 4096 + t0 + tx] =
        tile[tx][ty + i * 8];
}

// ---------- softmax for one q-group (swapped-QK layout) ----------
// Lane (qr,kg) holds S[q=qg][kv0 + {kg*4+j, 16+kg*4+j}] in sA/sB (pre-scaled
// Q). Returns packed P fragment: dword u = (p[u], p[4+u]) — slot order
// matching perm(s) in VTg. No LDS round-trip.
__device__ __forceinline__ bf16x8 softmax_group(
    f32x4 sA, f32x4 sB, int kv0, int qg, bool full,
    float& mr, float& lr, f32x4* o, int kg) {
  float v[8];
#pragma unroll
  for (int j = 0; j < 4; ++j) v[j] = sA[j];
#pragma unroll
  for (int j = 0; j < 4; ++j) v[4 + j] = sB[j];
  if (!full) {
#pragma unroll
    for (int j = 0; j < 4; ++j) {
      if (kv0 + kg * 4 + j > qg) v[j] = -1e30f;
      if (kv0 + 16 + kg * 4 + j > qg) v[4 + j] = -1e30f;
    }
  }
  float tm = v[0];
#pragma unroll
  for (int j = 1; j < 8; ++j) tm = fmaxf(tm, v[j]);
  tm = fmaxf(tm, __shfl_xor(tm, 16));
  tm = fmaxf(tm, __shfl_xor(tm, 32));
  float mref;
  if (__all(tm - mr <= 8.0f)) {
    mref = mr;  // defer-max (T13)
  } else {
    float mnew = fmaxf(mr, tm);
    float corr = __expf(mr - mnew);
    lr *= corr;
    float c0 = __shfl(corr, kg * 4 + 0);
    float c1 = __shfl(corr, kg * 4 + 1);
    float c2 = __shfl(corr, kg * 4 + 2);
    float c3 = __shfl(corr, kg * 4 + 3);
#pragma unroll
    for (int n = 0; n < 16; ++n) {
      o[n][0] *= c0; o[n][1] *= c1; o[n][2] *= c2; o[n][3] *= c3;
    }
    mr = mnew; mref = mnew;
  }
  float p[8];
#pragma unroll
  for (int j = 0; j < 8; ++j) p[j] = __expf(v[j] - mref);
  float ps = 0.f;
#pragma unroll
  for (int j = 0; j < 8; ++j) ps += p[j];
  ps += __shfl_xor(ps, 16);
  ps += __shfl_xor(ps, 32);
  lr += ps;
  union { u32x4 u; bf16x8 b; } pk;
#pragma unroll
  for (int u2 = 0; u2 < 4; ++u2)
    pk.u[u2] = (uint_t)f2bf(p[u2]) | ((uint_t)f2bf(p[4 + u2]) << 16);
  return pk.b;
}

// ---------- 5) causal flash attention + sigmoid gate ----------
// QBLK=64 (4 waves x 16 q), KVBLK=32. Raw-barrier pipeline (T3/T4): K
// double-buffered via gload_lds (32 KB); V SINGLE-buffered (16 KB), staged
// global->reg (one phase early, 64B/lane rows of VTg) -> ds_write after
// barrier A. Per tile: vmcnt(0) [phase-old loads only] + s_barrier A ->
// V ds_write + issue K(t+1)/V(t+1) -> lgkmcnt(0) + s_barrier B (NO vmem
// drain: next-tile loads stay in flight across B and the whole compute —
// the __syncthreads vmcnt(0) drain was the round-7/11/12 failure mode) ->
// QK/softmax/PV. LDS 48 KB + ~140 VGPR -> 3 blocks/CU (round-13 post-mortem:
// kernel is stall-bound at 45% pipe utilization, not LDS-bound; occupancy
// is the lever). ds_write chunk permutation == round-10's verified pair.
__global__ __launch_bounds__(256, 3) void attn_kernel(
    const ushort_t* __restrict__ qkv, const ushort_t* __restrict__ VTg,
    ushort_t* __restrict__ A2) {
  const int id = blockIdx.x;
  const int g8 = id & 255, kk = id >> 8;
  const int x = g8 >> 4;
  const int h = ((g8 & 1) << 3) | ((g8 >> 1) & 7);
  const int qt = (3 - kk) * 16 + ((kk & 1) ? (15 - x) : x);
  const int kvh = g8 & 1;  // == h>>3
  const int tid = threadIdx.x;
  const int lane = tid & 63;
  const int wid = tid >> 6;
  const int qr = lane & 15, kg = lane >> 4;

  __shared__ __align__(16) ushort_t Ks[2][32 * 256];  // 32 KB, chunk-XOR swz
  __shared__ __align__(16) ushort_t Vt[256 * 32];     // 16 KB, single buffer

  const int q0 = qt * 64;
  const int myq0 = q0 + wid * 16;
  // V staging: thread owns V^T row d = tid (64 B / tile), chunk-permuted write
  const ushort_t* vsrc = VTg + (size_t)kvh * 1048576 + (size_t)tid * 4096;
  char* vdst = (char*)&Vt[0] + tid * 64;
  const int vpx = (tid >> 1) & 3;

  bf16x8 qf[8];
#pragma unroll
  for (int kd = 0; kd < 8; ++kd)
    qf[kd] = *(const bf16x8*)(qkv + (size_t)(myq0 + qr) * 9216 + h * 512 +
                              kd * 32 + kg * 8);

  f32x4 o[16] = {};
  float mr = -1e30f, lr = 0.f;

  const int nt = qt * 2 + 2;

  // prologue: issue K(0) stage + V(0) register loads
#pragma unroll
  for (int t = 0; t < 4; ++t) {
    int c = (t * 4 + wid) * 64 + lane;
    int r = c >> 5, dc = c & 31;
    int dcs = dc ^ (r & 7);
    gload_lds16(qkv + (size_t)r * 9216 + 8192 + kvh * 256 + dcs * 8,
                &Ks[0][(t * 4 + wid) * 512]);
  }
  u32x4 va = *(const u32x4*)(vsrc);
  u32x4 vb = *(const u32x4*)(vsrc + 8);
  u32x4 vc = *(const u32x4*)(vsrc + 16);
  u32x4 vd = *(const u32x4*)(vsrc + 24);

  for (int kt = 0; kt < nt; ++kt) {
    const int kv0 = kt * 32;

    // ---- barrier A: K(kt) in LDS, V(kt) regs landed (aged one phase) ----
    asm volatile("s_waitcnt vmcnt(0)" ::: "memory");
    __builtin_amdgcn_s_barrier();
    __builtin_amdgcn_sched_barrier(0);

    // ---- write V(kt) into single Vt (all PV(kt-1) reads done before A) ----
    *(u32x4*)(vdst + ((0 ^ vpx) * 16)) = va;
    *(u32x4*)(vdst + ((1 ^ vpx) * 16)) = vb;
    *(u32x4*)(vdst + ((2 ^ vpx) * 16)) = vc;
    *(u32x4*)(vdst + ((3 ^ vpx) * 16)) = vd;

    // ---- issue K(kt+1) stage + V(kt+1) reg loads (stay in flight across B) ----
    if (kt + 1 < nt) {
      const int kv0n = kv0 + 32;
#pragma unroll
      for (int t = 0; t < 4; ++t) {
        int c = (t * 4 + wid) * 64 + lane;
        int r = c >> 5, dc = c & 31;
        int dcs = dc ^ (r & 7);
        gload_lds16(qkv + (size_t)(kv0n + r) * 9216 + 8192 + kvh * 256 + dcs * 8,
                    &Ks[(kt + 1) & 1][(t * 4 + wid) * 512]);
      }
      va = *(const u32x4*)(vsrc + kv0n);
      vb = *(const u32x4*)(vsrc + kv0n + 8);
      vc = *(const u32x4*)(vsrc + kv0n + 16);
      vd = *(const u32x4*)(vsrc + kv0n + 24);
    }

    // ---- barrier B: V(kt) writes visible; NO vmem drain ----
    asm volatile("s_waitcnt lgkmcnt(0)" ::: "memory");
    __builtin_amdgcn_sched_barrier(0);
    __builtin_amdgcn_s_barrier();
    __builtin_amdgcn_sched_barrier(0);

    // ---- compute tile kt ----
    const bool active = (kv0 <= myq0 + 15);  // wave-uniform causal skip
    if (active) {
      const char* ksb = (const char*)&Ks[kt & 1][0];
      const int kxor = (qr & 7) << 4;
      const int kbase = qr * 512;
      f32x4 s0 = {0.f, 0.f, 0.f, 0.f}, s1 = {0.f, 0.f, 0.f, 0.f};
      __builtin_amdgcn_s_setprio(1);
#pragma unroll
      for (int kd = 0; kd < 8; ++kd) {
        int off = kbase + ((kd * 64 + kg * 16) ^ kxor);
        bf16x8 kf0 = *(const bf16x8*)(ksb + off);
        bf16x8 kf1 = *(const bf16x8*)(ksb + off + 8192);
        s0 = __builtin_amdgcn_mfma_f32_16x16x32_bf16(kf0, qf[kd], s0, 0, 0, 0);
        s1 = __builtin_amdgcn_mfma_f32_16x16x32_bf16(kf1, qf[kd], s1, 0, 0, 0);
      }
      __builtin_amdgcn_s_setprio(0);

      const bool full = (kv0 + 31 <= myq0);
      bf16x8 pf = softmax_group(s0, s1, kv0, myq0 + qr, full, mr, lr, o, kg);

      const char* vtb = (const char*)&Vt[0];
      const int vxor = (qr >> 1) & 3;  // read-side chunk permutation
      __builtin_amdgcn_s_setprio(1);
#pragma unroll
      for (int n = 0; n < 16; ++n) {
        int dcol = n * 16 + qr;
        bf16x8 vf = *(const bf16x8*)(vtb + dcol * 64 + ((kg ^ vxor) * 16));
        o[n] = __builtin_amdgcn_mfma_f32_16x16x32_bf16(pf, vf, o[n], 0, 0, 0);
      }
      __builtin_amdgcn_s_setprio(0);
    }
  }

  // epilogue: 1/l, sigmoid gate, bf16 store
  float rl[4];
#pragma unroll
  for (int j = 0; j < 4; ++j) rl[j] = 1.0f / __shfl(lr, kg * 4 + j);
#pragma unroll
  for (int n = 0; n < 16; ++n) {
    int d = n * 16 + qr;
#pragma unroll
    for (int j = 0; j < 4; ++j) {
      int t = myq0 + kg * 4 + j;
      float val = o[n][j] * rl[j];
      float g2 = bf2f(qkv[(size_t)t * 9216 + h * 512 + 256 + d]);
      val *= 1.0f / (1.0f + __expf(-g2));
      A2[(size_t)t * 4096 + h * 256 + d] = f2bf(val);
    }
  }
}

// ---------- launch ----------
extern "C" void kernel_launch(void* const* d_in, const int* in_sizes, int n_in,
                              void* d_out, int out_size, void* d_ws, size_t ws_size,
                              hipStream_t stream) {
  const float* hidden = (const float*)d_in[0];
  const int* positions = (const int*)d_in[1];
  const float* w_qkv = (const float*)d_in[2];
  const float* w_o = (const float*)d_in[3];
  const float* q_norm_w = (const float*)d_in[4];
  const float* k_norm_w = (const float*)d_in[5];

  char* ws = (char*)d_ws;
  ushort_t* hb    = (ushort_t*)ws;                          // hidden bf16 (dead after GEMM1)
  ushort_t* VTg   = (ushort_t*)ws;                          // aliases hb: V^T (2,256,4096) bf16
  ushort_t* wqkvT = (ushort_t*)(ws + 16777216);             // w_qkv^T bf16 (9216,2048)
  ushort_t* woT   = (ushort_t*)(ws + 54525952);             // w_o^T bf16 (2048,4096)
  ushort_t* qkvb  = (ushort_t*)(ws + 71303168);             // qkv bf16 (4096,9216)
  ushort_t* A2    = (ushort_t*)(ws + 146800640);            // gated attn bf16 (4096,4096)

  hipLaunchKernelGGL(cast_bf16_kernel, dim3(4096), dim3(256), 0, stream,
                     hidden, hb, 1048576);
  hipLaunchKernelGGL(transpose_cast_kernel, dim3(288, 64), dim3(32, 8), 0, stream,
                     w_qkv, wqkvT, 2048, 9216);
  hipLaunchKernelGGL(transpose_cast_kernel, dim3(64, 128), dim3(32, 8), 0, stream,
                     w_o, woT, 4096, 2048);
  hipLaunchKernelGGL((gemm_bt_kernel<1>), dim3(2304), dim3(256), 0, stream,
                     hb, wqkvT, (void*)qkvb, 4096, 9216, 2048, 72, 288);
  hipLaunchKernelGGL(normrope_kernel, dim3(18432), dim3(256), 0, stream,
                     qkvb, positions, q_norm_w, k_norm_w);
  hipLaunchKernelGGL(vtranspose_kernel, dim3(128, 8, 2), dim3(32, 8), 0, stream,
                     qkvb, VTg);
  hipLaunchKernelGGL(attn_kernel, dim3(1024), dim3(256), 0, stream,
                     qkvb, VTg, A2);
  hipLaunchKernelGGL((gemm_bt_kernel<0>), dim3(512), dim3(256), 0, stream,
                     A2, woT, d_out, 4096, 2048, 4096, 16, 64);
}

// Round 15
// 600.178 us; speedup vs baseline: 1.8555x; 1.0752x over previous
//
#include <hip/hip_runtime.h>

typedef __attribute__((ext_vector_type(4))) float f32x4;
typedef __attribute__((ext_vector_type(8))) __bf16 bf16x8;
typedef unsigned short ushort_t;
typedef unsigned int uint_t;
typedef __attribute__((ext_vector_type(4))) uint_t u32x4;

// ---------- bf16 helpers (manual, RNE) ----------
__device__ __forceinline__ float bf2f(ushort_t u) {
  union { uint_t i; float f; } v; v.i = ((uint_t)u) << 16; return v.f;
}
__device__ __forceinline__ ushort_t f2bf(float f) {
  union { float f; uint_t i; } v; v.f = f;
  uint_t x = v.i;
  return (ushort_t)((x + 0x7fffu + ((x >> 16) & 1u)) >> 16);
}

// ---------- async global->LDS, 16B ----------
__device__ __forceinline__ void gload_lds16(const void* g, void* l) {
  __builtin_amdgcn_global_load_lds(
      (const __attribute__((address_space(1))) void*)g,
      (__attribute__((address_space(3))) void*)l, 16, 0, 0);
}

// ---------- 1) fp32 -> bf16 cast (8 elems/thread) ----------
__global__ __launch_bounds__(256) void cast_bf16_kernel(
    const float* __restrict__ in, ushort_t* __restrict__ out, int n8) {
  int i = blockIdx.x * 256 + threadIdx.x;
  if (i >= n8) return;
  float4 a = ((const float4*)in)[i * 2];
  float4 b = ((const float4*)in)[i * 2 + 1];
  ushort4 o0 = make_ushort4(f2bf(a.x), f2bf(a.y), f2bf(a.z), f2bf(a.w));
  ushort4 o1 = make_ushort4(f2bf(b.x), f2bf(b.y), f2bf(b.z), f2bf(b.w));
  ((ushort4*)out)[i * 2] = o0;
  ((ushort4*)out)[i * 2 + 1] = o1;
}

// ---------- 2) transpose + cast: in (R,C) fp32 -> out (C,R) bf16 ----------
__global__ __launch_bounds__(256) void transpose_cast_kernel(
    const float* __restrict__ in, ushort_t* __restrict__ out, int R, int C) {
  __shared__ float tile[32][33];
  int tx = threadIdx.x, ty = threadIdx.y;
  int c0 = blockIdx.x * 32, r0 = blockIdx.y * 32;
#pragma unroll
  for (int i = 0; i < 4; ++i)
    tile[ty + i * 8][tx] = in[(size_t)(r0 + ty + i * 8) * C + c0 + tx];
  __syncthreads();
#pragma unroll
  for (int i = 0; i < 4; ++i)
    out[(size_t)(c0 + ty + i * 8) * R + r0 + tx] = f2bf(tile[tx][ty + i * 8]);
}

// ---------- 3a) legacy GEMM (m97-class): C = A * BT^T, 128^2 tile ----------
template <int OUT_BF16>
__global__ __launch_bounds__(256, 2) void gemm_bt_kernel(
    const ushort_t* __restrict__ A, const ushort_t* __restrict__ BT,
    void* __restrict__ Cout, int M, int N, int K, int nx, int cpx) {
  const int lin = blockIdx.x;
  const int swz = (lin & 7) * cpx + (lin >> 3);
  const int bx = swz % nx, by = swz / nx;

  __shared__ ushort_t As[128 * 32];
  __shared__ ushort_t Bs[128 * 32];
  const int tid = threadIdx.x;
  const int lane = tid & 63;
  const int wid = tid >> 6;
  const int wr = wid >> 1, wc = wid & 1;
  const int qr = lane & 15, kg = lane >> 4;
  const size_t arow = (size_t)by * 128;
  const size_t brow = (size_t)bx * 128;

  f32x4 acc[4][4] = {};

  for (int k0 = 0; k0 < K; k0 += 32) {
    __syncthreads();
#pragma unroll
    for (int t = 0; t < 2; ++t) {
      int c = (t * 4 + wid) * 64 + lane;
      int r = c >> 2, kc = (c & 3) * 8;
      gload_lds16(A + (arow + r) * K + k0 + kc, &As[(t * 4 + wid) * 512]);
      gload_lds16(BT + (brow + r) * K + k0 + kc, &Bs[(t * 4 + wid) * 512]);
    }
    __syncthreads();
    bf16x8 af[4], bfr[4];
#pragma unroll
    for (int m = 0; m < 4; ++m)
      af[m] = *(const bf16x8*)&As[(wr * 64 + m * 16 + qr) * 32 + kg * 8];
#pragma unroll
    for (int n = 0; n < 4; ++n)
      bfr[n] = *(const bf16x8*)&Bs[(wc * 64 + n * 16 + qr) * 32 + kg * 8];
#pragma unroll
    for (int m = 0; m < 4; ++m)
#pragma unroll
      for (int n = 0; n < 4; ++n)
        acc[m][n] = __builtin_amdgcn_mfma_f32_16x16x32_bf16(af[m], bfr[n], acc[m][n], 0, 0, 0);
  }

#pragma unroll
  for (int m = 0; m < 4; ++m)
#pragma unroll
    for (int n = 0; n < 4; ++n)
#pragma unroll
      for (int j = 0; j < 4; ++j) {
        size_t row = arow + wr * 64 + m * 16 + kg * 4 + j;
        size_t col = brow + wc * 64 + n * 16 + qr;
        float v = acc[m][n][j];
        if (OUT_BF16) ((ushort_t*)Cout)[row * N + col] = f2bf(v);
        else ((float*)Cout)[row * N + col] = v;
      }
}

// ---------- 3b) 8-phase 256^2 GEMM (T2+T3+T4+T5), bf16 out ----------
// BM=BN=256, BK=64, 8 waves (2M x 4N), per-wave C 128x64 (acc[8][4]).
// LDS 128 KB: 8 regions of 16 KB (buf{0,1} x {A0,A1,B0,B1}).
// Chunk-XOR swizzle: LDS chunk (row, ci) holds global col-chunk ci^(row&7)
// (pre-swizzled global source, linear gload dest; read XOR (ks*4+kg)^(qr&7)
// -> 8 lanes hit 8 distinct 16B chunks = all 32 banks, conflict-free).
// Stage schedule (iter i computes steps e=2i [buf0, ph0-3], o=2i+1 [buf1,
// ph4-7]): ph0: buf1.B0<-o, ph1: buf1.B1<-o, ph3: buf0.A<-e+2 (x2),
// ph4: buf0.B<-e+2 (x2), ph7: buf1.A<-e+3 (x2). vmcnt(4) BEFORE the
// ph3/ph7 end barriers (vmcnt must precede a barrier so OTHER threads'
// staged chunks are known-landed before the next phase's ds_reads).
// Final iter: only ph0/ph1 stages; vmcnt(0) at ph3 tail.
#define G8_BAR() { __builtin_amdgcn_sched_barrier(0); __builtin_amdgcn_s_barrier(); __builtin_amdgcn_sched_barrier(0); }
#define G8_RDA(base, mh) { _Pragma("unroll") for (int mm = 0; mm < 4; ++mm) { const int r_ = (base) + ((mh) * 64 + mm * 16 + qr) * 128; af[mm][0] = *(const bf16x8*)(smem + r_ + kgx0); af[mm][1] = *(const bf16x8*)(smem + r_ + kgx1); } }
#define G8_RDB(base, nh) { _Pragma("unroll") for (int nn = 0; nn < 2; ++nn) { const int r_ = (base) + (rbo + (nh) * 32 + nn * 16 + qr) * 128; bfr[nn][0] = *(const bf16x8*)(smem + r_ + kgx0); bfr[nn][1] = *(const bf16x8*)(smem + r_ + kgx1); } }
#define G8_MFMA(mh, nh) { __builtin_amdgcn_s_setprio(1); _Pragma("unroll") for (int mm = 0; mm < 4; ++mm) _Pragma("unroll") for (int nn = 0; nn < 2; ++nn) { f32x4 a_ = acc[(mh) * 4 + mm][(nh) * 2 + nn]; a_ = __builtin_amdgcn_mfma_f32_16x16x32_bf16(af[mm][0], bfr[nn][0], a_, 0, 0, 0); a_ = __builtin_amdgcn_mfma_f32_16x16x32_bf16(af[mm][1], bfr[nn][1], a_, 0, 0, 0); acc[(mh) * 4 + mm][(nh) * 2 + nn] = a_; } __builtin_amdgcn_s_setprio(0); }

__global__ __launch_bounds__(512, 2) void gemm8_kernel(
    const ushort_t* __restrict__ A, const ushort_t* __restrict__ BT,
    ushort_t* __restrict__ C, int M, int N, int K, int nx, int cpx) {
  __shared__ __align__(16) char smem[131072];
  const int lin = blockIdx.x;
  const int swz = (lin & 7) * cpx + (lin >> 3);
  const int bx = swz % nx, by = swz / nx;
  const int tid = threadIdx.x;
  const int lane = tid & 63;
  const int wid = tid >> 6;
  const int wr = wid >> 2, wc = wid & 3;
  const int qr = lane & 15, kg = lane >> 4;
  const int rbo = (wc & 1) * 64;
  const int kgx0 = (kg << 4) ^ ((qr & 7) << 4);
  const int kgx1 = ((kg | 4) << 4) ^ ((qr & 7) << 4);
  const int ab0 = wr * 16384, ab1 = 65536 + wr * 16384;
  const int bb0 = 32768 + (wc >> 1) * 16384;
  const int bb1 = 65536 + 32768 + (wc >> 1) * 16384;
  const int srow = tid >> 3;
  const int scol = ((tid & 7) ^ (srow & 7)) << 3;

  const ushort_t* Ab = A + (size_t)(by * 256 + srow) * K + scol;
  const ushort_t* Bb = BT + (size_t)(bx * 256 + srow) * K + scol;
  const size_t r64 = (size_t)64 * K;
  const size_t r128 = (size_t)128 * K;

  f32x4 acc[8][4] = {};
  bf16x8 af[4][2], bfr[2][2];

  auto stA = [&](int h, int s, int rb) {
    const ushort_t* p = Ab + (h ? r128 : 0) + s * 64;
    gload_lds16(p, smem + rb + tid * 16);
    gload_lds16(p + r64, smem + rb + 8192 + tid * 16);
  };
  auto stB = [&](int h, int s, int rb) {
    const ushort_t* p = Bb + (h ? r128 : 0) + s * 64;
    gload_lds16(p, smem + rb + tid * 16);
    gload_lds16(p + r64, smem + rb + 8192 + tid * 16);
  };

  // prologue: step 0 -> buf0 (4 half-tiles), step 1 A -> buf1 (2)
  stA(0, 0, 0); stA(1, 0, 16384); stB(0, 0, 32768); stB(1, 0, 49152);
  stA(0, 1, 65536); stA(1, 1, 81920);
  asm volatile("s_waitcnt vmcnt(4)" ::: "memory");
  G8_BAR()

#pragma unroll 1
  for (int it = 0; it < 16; ++it) {
    const int e = it * 2;
    const bool nl = (it < 15);
    // ph0: Q(0,0) on buf0; stage buf1.B0 <- e+1
    G8_RDA(ab0, 0) G8_RDB(bb0, 0)
    stB(0, e + 1, 98304);
    G8_BAR() G8_MFMA(0, 0) G8_BAR()
    // ph1: Q(0,1); stage buf1.B1 <- e+1
    G8_RDB(bb0, 1)
    stB(1, e + 1, 114688);
    G8_BAR() G8_MFMA(0, 1) G8_BAR()
    // ph2: Q(1,1)
    G8_RDA(ab0, 1)
    G8_BAR() G8_MFMA(1, 1) G8_BAR()
    // ph3: Q(1,0); stage buf0.A <- e+2; vmcnt before end barrier
    G8_RDB(bb0, 0)
    if (nl) { stA(0, e + 2, 0); stA(1, e + 2, 16384); }
    G8_BAR() G8_MFMA(1, 0)
    if (nl) { asm volatile("s_waitcnt vmcnt(4)" ::: "memory"); }
    else    { asm volatile("s_waitcnt vmcnt(0)" ::: "memory"); }
    G8_BAR()
    // ph4: Q(0,0) on buf1; stage buf0.B <- e+2
    G8_RDA(ab1, 0) G8_RDB(bb1, 0)
    if (nl) { stB(0, e + 2, 32768); stB(1, e + 2, 49152); }
    G8_BAR() G8_MFMA(0, 0) G8_BAR()
    // ph5: Q(0,1)
    G8_RDB(bb1, 1)
    G8_BAR() G8_MFMA(0, 1) G8_BAR()
    // ph6: Q(1,1)
    G8_RDA(ab1, 1)
    G8_BAR() G8_MFMA(1, 1) G8_BAR()
    // ph7: Q(1,0); stage buf1.A <- e+3; vmcnt before end barrier
    G8_RDB(bb1, 0)
    if (nl) { stA(0, e + 3, 65536); stA(1, e + 3, 81920); }
    G8_BAR() G8_MFMA(1, 0)
    asm volatile("s_waitcnt vmcnt(4)" ::: "memory");
    G8_BAR()
  }

  // epilogue: bf16 C write
#pragma unroll
  for (int m = 0; m < 8; ++m)
#pragma unroll
    for (int n = 0; n < 4; ++n)
#pragma unroll
      for (int j = 0; j < 4; ++j) {
        size_t row = (size_t)by * 256 + wr * 128 + m * 16 + kg * 4 + j;
        size_t col = (size_t)bx * 256 + wc * 64 + n * 16 + qr;
        C[row * N + col] = f2bf(acc[m][n][j]);
      }
}

// ---------- 4) fused Gemma-RMSNorm + RoPE on q/k rows of qkv, in place ----------
// q rows (idx<16) pre-scaled by 1/sqrt(D)=1/16 (exact in bf16).
__global__ __launch_bounds__(256) void normrope_kernel(
    ushort_t* __restrict__ qkv, const int* __restrict__ positions,
    const float* __restrict__ qw, const float* __restrict__ kw) {
  const int wv = blockIdx.x * 4 + (threadIdx.x >> 6);
  const int lane = threadIdx.x & 63;
  const int t = wv / 18;
  const int idx = wv % 18;
  size_t base;
  const float* w;
  float sc;
  if (idx < 16) { base = (size_t)t * 9216 + idx * 512; w = qw; sc = 0.0625f; }
  else { base = (size_t)t * 9216 + 8192 + (size_t)(idx - 16) * 256; w = kw; sc = 1.0f; }

  ushort4 raw = *(const ushort4*)(qkv + base + lane * 4);
  float x0 = bf2f(raw.x), x1 = bf2f(raw.y), x2 = bf2f(raw.z), x3 = bf2f(raw.w);
  float ss = x0 * x0 + x1 * x1 + x2 * x2 + x3 * x3;
#pragma unroll
  for (int off = 1; off < 64; off <<= 1) ss += __shfl_xor(ss, off);
  float inv = rsqrtf(ss * (1.0f / 256.0f) + 1e-6f);
  const int d0 = lane * 4;
  float xn[4] = { x0 * inv * (1.f + w[d0]), x1 * inv * (1.f + w[d0 + 1]),
                  x2 * inv * (1.f + w[d0 + 2]), x3 * inv * (1.f + w[d0 + 3]) };
  float pn[4];
#pragma unroll
  for (int j = 0; j < 4; ++j) pn[j] = __shfl_xor(xn[j], 8);
  if (lane < 16) {
    const float pos = (float)positions[t];
#pragma unroll
    for (int j = 0; j < 4; ++j) {
      int d = d0 + j;
      int i = d & 31;
      float invf = __expf(-(float)i * 0.28782313662425574f);  // 10000^(-i/32)
      float fr = pos * invf;
      float s, c;
      sincosf(fr, &s, &c);
      xn[j] = (d < 32) ? (xn[j] * c - pn[j] * s) : (xn[j] * c + pn[j] * s);
    }
  }
  ushort4 o = make_ushort4(f2bf(xn[0] * sc), f2bf(xn[1] * sc),
                           f2bf(xn[2] * sc), f2bf(xn[3] * sc));
  *(ushort4*)(qkv + base + lane * 4) = o;
}

// ---------- 4b) V global transpose with interleaved slot order ----------
// VTg[kvh][d][t0 + s] = V[t0 + perm(s)][kvh][d],
// perm(s) = ((s&1)<<4) + ((s>>3)<<2) + ((s&7)>>1)  (verified rounds 5/6/8/10).
__global__ __launch_bounds__(256) void vtranspose_kernel(
    const ushort_t* __restrict__ qkv, ushort_t* __restrict__ VTg) {
  __shared__ ushort_t tile[32][34];
  const int tx = threadIdx.x, ty = threadIdx.y;
  const int t0 = blockIdx.x * 32, d0 = blockIdx.y * 32, kvh = blockIdx.z;
#pragma unroll
  for (int i = 0; i < 4; ++i) {
    int s = ty + i * 8;
    int kvl = ((s & 1) << 4) + ((s >> 3) << 2) + ((s & 7) >> 1);  // perm(s)
    tile[s][tx] = qkv[(size_t)(t0 + kvl) * 9216 + 8704 + kvh * 256 + d0 + tx];
  }
  __syncthreads();
#pragma unroll
  for (int i = 0; i < 4; ++i)
    VTg[(size_t)kvh * 1048576 + (size_t)(d0 + ty + i * 8) * 4096 + t0 + tx] =
        tile[tx][ty + i * 8];
}

// ---------- softmax for one q-group (swapped-QK layout) ----------
__device__ __forceinline__ bf16x8 softmax_group(
    f32x4 sA, f32x4 sB, int kv0, int qg, bool full,
    float& mr, float& lr, f32x4* o, int kg) {
  float v[8];
#pragma unroll
  for (int j = 0; j < 4; ++j) v[j] = sA[j];
#pragma unroll
  for (int j = 0; j < 4; ++j) v[4 + j] = sB[j];
  if (!full) {
#pragma unroll
    for (int j = 0; j < 4; ++j) {
      if (kv0 + kg * 4 + j > qg) v[j] = -1e30f;
      if (kv0 + 16 + kg * 4 + j > qg) v[4 + j] = -1e30f;
    }
  }
  float tm = v[0];
#pragma unroll
  for (int j = 1; j < 8; ++j) tm = fmaxf(tm, v[j]);
  tm = fmaxf(tm, __shfl_xor(tm, 16));
  tm = fmaxf(tm, __shfl_xor(tm, 32));
  float mref;
  if (__all(tm - mr <= 8.0f)) {
    mref = mr;  // defer-max (T13)
  } else {
    float mnew = fmaxf(mr, tm);
    float corr = __expf(mr - mnew);
    lr *= corr;
    float c0 = __shfl(corr, kg * 4 + 0);
    float c1 = __shfl(corr, kg * 4 + 1);
    float c2 = __shfl(corr, kg * 4 + 2);
    float c3 = __shfl(corr, kg * 4 + 3);
#pragma unroll
    for (int n = 0; n < 16; ++n) {
      o[n][0] *= c0; o[n][1] *= c1; o[n][2] *= c2; o[n][3] *= c3;
    }
    mr = mnew; mref = mnew;
  }
  float p[8];
#pragma unroll
  for (int j = 0; j < 8; ++j) p[j] = __expf(v[j] - mref);
  float ps = 0.f;
#pragma unroll
  for (int j = 0; j < 8; ++j) ps += p[j];
  ps += __shfl_xor(ps, 16);
  ps += __shfl_xor(ps, 32);
  lr += ps;
  union { u32x4 u; bf16x8 b; } pk;
#pragma unroll
  for (int u2 = 0; u2 < 4; ++u2)
    pk.u[u2] = (uint_t)f2bf(p[u2]) | ((uint_t)f2bf(p[4 + u2]) << 16);
  return pk.b;
}

// ---------- 5) causal flash attention + sigmoid gate (round-10 version) ----------
// QBLK=64 (4 waves x 16 q), KVBLK=32. K and V staged via global_load_lds into
// double buffers; single barrier/tile BEFORE the t+1 issue. Vt chunk positions
// XOR-permuted (chunk (d,k) at slot d*4 + (k ^ ((d>>1)&3))); staging inverts
// the permutation in the per-lane GLOBAL source; LDS dest linear (rule #21).
__global__ __launch_bounds__(256, 2) void attn_kernel(
    const ushort_t* __restrict__ qkv, const ushort_t* __restrict__ VTg,
    ushort_t* __restrict__ A2) {
  const int id = blockIdx.x;
  const int g8 = id & 255, kk = id >> 8;
  const int x = g8 >> 4;
  const int h = ((g8 & 1) << 3) | ((g8 >> 1) & 7);
  const int qt = (3 - kk) * 16 + ((kk & 1) ? (15 - x) : x);
  const int kvh = g8 & 1;  // == h>>3
  const int tid = threadIdx.x;
  const int lane = tid & 63;
  const int wid = tid >> 6;
  const int qr = lane & 15, kg = lane >> 4;

  __shared__ __align__(16) ushort_t Ks[2][32 * 256];  // [kv][d], chunk-XOR swz
  __shared__ __align__(16) ushort_t Vt[2][256 * 32];  // [d][slot], chunk-XOR swz

  const int q0 = qt * 64;
  const int myq0 = q0 + wid * 16;
  const ushort_t* vtg = VTg + (size_t)kvh * 1048576;

  bf16x8 qf[8];
#pragma unroll
  for (int kd = 0; kd < 8; ++kd)
    qf[kd] = *(const bf16x8*)(qkv + (size_t)(myq0 + qr) * 9216 + h * 512 +
                              kd * 32 + kg * 8);

  f32x4 o[16] = {};
  float mr = -1e30f, lr = 0.f;

  const int nt = qt * 2 + 2;

  // prologue: issue tile 0 into buf 0
#pragma unroll
  for (int t = 0; t < 4; ++t) {
    int c = (t * 4 + wid) * 64 + lane;
    int r = c >> 5, dc = c & 31;
    int dcs = dc ^ (r & 7);
    gload_lds16(qkv + (size_t)r * 9216 + 8192 + kvh * 256 + dcs * 8,
                &Ks[0][(t * 4 + wid) * 512]);
  }
#pragma unroll
  for (int t = 0; t < 4; ++t) {
    int c = (t * 4 + wid) * 64 + lane;
    int d = c >> 2, k2 = c & 3;
    int kc = k2 ^ ((d >> 1) & 3);  // inverse chunk permutation in source
    gload_lds16(vtg + (size_t)d * 4096 + kc * 8,
                &Vt[0][(t * 4 + wid) * 512]);
  }

  int buf = 0;
  for (int kt = 0; kt < nt; ++kt) {
    const int kv0 = kt * 32;
    __syncthreads();  // tile kt staged (loads aged one full compute phase)

    // ---- issue stage of tile t+1 into the other buffer ----
    if (kt + 1 < nt) {
      const int kv0n = kv0 + 32;
#pragma unroll
      for (int t = 0; t < 4; ++t) {
        int c = (t * 4 + wid) * 64 + lane;
        int r = c >> 5, dc = c & 31;
        int dcs = dc ^ (r & 7);
        gload_lds16(qkv + (size_t)(kv0n + r) * 9216 + 8192 + kvh * 256 + dcs * 8,
                    &Ks[buf ^ 1][(t * 4 + wid) * 512]);
      }
#pragma unroll
      for (int t = 0; t < 4; ++t) {
        int c = (t * 4 + wid) * 64 + lane;
        int d = c >> 2, k2 = c & 3;
        int kc = k2 ^ ((d >> 1) & 3);
        gload_lds16(vtg + (size_t)d * 4096 + kv0n + kc * 8,
                    &Vt[buf ^ 1][(t * 4 + wid) * 512]);
      }
    }
    __builtin_amdgcn_sched_barrier(0);

    // ---- compute tile t ----
    const bool active = (kv0 <= myq0 + 15);  // wave-uniform causal skip
    if (active) {
      const char* ksb = (const char*)&Ks[buf][0];
      const int kxor = (qr & 7) << 4;
      const int kbase = qr * 512;
      f32x4 s0 = {0.f, 0.f, 0.f, 0.f}, s1 = {0.f, 0.f, 0.f, 0.f};
      __builtin_amdgcn_s_setprio(1);
#pragma unroll
      for (int kd = 0; kd < 8; ++kd) {
        int off = kbase + ((kd * 64 + kg * 16) ^ kxor);
        bf16x8 kf0 = *(const bf16x8*)(ksb + off);
        bf16x8 kf1 = *(const bf16x8*)(ksb + off + 8192);
        s0 = __builtin_amdgcn_mfma_f32_16x16x32_bf16(kf0, qf[kd], s0, 0, 0, 0);
        s1 = __builtin_amdgcn_mfma_f32_16x16x32_bf16(kf1, qf[kd], s1, 0, 0, 0);
      }
      __builtin_amdgcn_s_setprio(0);

      const bool full = (kv0 + 31 <= myq0);
      bf16x8 pf = softmax_group(s0, s1, kv0, myq0 + qr, full, mr, lr, o, kg);

      const char* vtb = (const char*)&Vt[buf][0];
      const int vxor = (qr >> 1) & 3;  // read-side chunk permutation
      __builtin_amdgcn_s_setprio(1);
#pragma unroll
      for (int n = 0; n < 16; ++n) {
        int dcol = n * 16 + qr;
        bf16x8 vf = *(const bf16x8*)(vtb + dcol * 64 + ((kg ^ vxor) * 16));
        o[n] = __builtin_amdgcn_mfma_f32_16x16x32_bf16(pf, vf, o[n], 0, 0, 0);
      }
      __builtin_amdgcn_s_setprio(0);
    }
    buf ^= 1;
  }

  // epilogue: 1/l, sigmoid gate, bf16 store
  float rl[4];
#pragma unroll
  for (int j = 0; j < 4; ++j) rl[j] = 1.0f / __shfl(lr, kg * 4 + j);
#pragma unroll
  for (int n = 0; n < 16; ++n) {
    int d = n * 16 + qr;
#pragma unroll
    for (int j = 0; j < 4; ++j) {
      int t = myq0 + kg * 4 + j;
      float val = o[n][j] * rl[j];
      float g2 = bf2f(qkv[(size_t)t * 9216 + h * 512 + 256 + d]);
      val *= 1.0f / (1.0f + __expf(-g2));
      A2[(size_t)t * 4096 + h * 256 + d] = f2bf(val);
    }
  }
}

// ---------- launch ----------
extern "C" void kernel_launch(void* const* d_in, const int* in_sizes, int n_in,
                              void* d_out, int out_size, void* d_ws, size_t ws_size,
                              hipStream_t stream) {
  const float* hidden = (const float*)d_in[0];
  const int* positions = (const int*)d_in[1];
  const float* w_qkv = (const float*)d_in[2];
  const float* w_o = (const float*)d_in[3];
  const float* q_norm_w = (const float*)d_in[4];
  const float* k_norm_w = (const float*)d_in[5];

  char* ws = (char*)d_ws;
  ushort_t* hb    = (ushort_t*)ws;                          // hidden bf16 (dead after GEMM1)
  ushort_t* VTg   = (ushort_t*)ws;                          // aliases hb: V^T (2,256,4096) bf16
  ushort_t* wqkvT = (ushort_t*)(ws + 16777216);             // w_qkv^T bf16 (9216,2048)
  ushort_t* woT   = (ushort_t*)(ws + 54525952);             // w_o^T bf16 (2048,4096)
  ushort_t* qkvb  = (ushort_t*)(ws + 71303168);             // qkv bf16 (4096,9216)
  ushort_t* A2    = (ushort_t*)(ws + 146800640);            // gated attn bf16 (4096,4096)

  hipLaunchKernelGGL(cast_bf16_kernel, dim3(4096), dim3(256), 0, stream,
                     hidden, hb, 1048576);
  hipLaunchKernelGGL(transpose_cast_kernel, dim3(288, 64), dim3(32, 8), 0, stream,
                     w_qkv, wqkvT, 2048, 9216);
  hipLaunchKernelGGL(transpose_cast_kernel, dim3(64, 128), dim3(32, 8), 0, stream,
                     w_o, woT, 4096, 2048);
  hipLaunchKernelGGL(gemm8_kernel, dim3(576), dim3(512), 0, stream,
                     hb, wqkvT, qkvb, 4096, 9216, 2048, 36, 72);
  hipLaunchKernelGGL(normrope_kernel, dim3(18432), dim3(256), 0, stream,
                     qkvb, positions, q_norm_w, k_norm_w);
  hipLaunchKernelGGL(vtranspose_kernel, dim3(128, 8, 2), dim3(32, 8), 0, stream,
                     qkvb, VTg);
  hipLaunchKernelGGL(attn_kernel, dim3(1024), dim3(256), 0, stream,
                     qkvb, VTg, A2);
  hipLaunchKernelGGL((gemm_bt_kernel<0>), dim3(512), dim3(256), 0, stream,
                     A2, woT, d_out, 4096, 2048, 4096, 16, 64);
}

// Round 16
// 594.527 us; speedup vs baseline: 1.8731x; 1.0095x over previous
//
#include <hip/hip_runtime.h>

typedef __attribute__((ext_vector_type(4))) float f32x4;
typedef __attribute__((ext_vector_type(8))) __bf16 bf16x8;
typedef unsigned short ushort_t;
typedef unsigned int uint_t;
typedef __attribute__((ext_vector_type(4))) uint_t u32x4;

// ---------- bf16 helpers ----------
__device__ __forceinline__ float bf2f(ushort_t u) {
  union { uint_t i; float f; } v; v.i = ((uint_t)u) << 16; return v.f;
}
__device__ __forceinline__ ushort_t f2bf(float f) {
  union { float f; uint_t i; } v; v.f = f;
  uint_t x = v.i;
  return (ushort_t)((x + 0x7fffu + ((x >> 16) & 1u)) >> 16);
}
// packed 2x fp32 -> bf16x2 (RNE), 1 instruction (T12 primitive)
__device__ __forceinline__ uint_t cvtpk(float lo, float hi) {
  uint_t r;
  asm("v_cvt_pk_bf16_f32 %0, %1, %2" : "=v"(r) : "v"(lo), "v"(hi));
  return r;
}
// 2^x in one v_exp_f32
__device__ __forceinline__ float fexp2(float x) {
  float r;
  asm("v_exp_f32 %0, %1" : "=v"(r) : "v"(x));
  return r;
}

// ---------- async global->LDS, 16B ----------
__device__ __forceinline__ void gload_lds16(const void* g, void* l) {
  __builtin_amdgcn_global_load_lds(
      (const __attribute__((address_space(1))) void*)g,
      (__attribute__((address_space(3))) void*)l, 16, 0, 0);
}

// ---------- 1) fp32 -> bf16 cast (8 elems/thread, packed cvt) ----------
__global__ __launch_bounds__(256) void cast_bf16_kernel(
    const float* __restrict__ in, uint_t* __restrict__ out, int n8) {
  int i = blockIdx.x * 256 + threadIdx.x;
  if (i >= n8) return;
  float4 a = ((const float4*)in)[i * 2];
  float4 b = ((const float4*)in)[i * 2 + 1];
  uint4 o;
  o.x = cvtpk(a.x, a.y); o.y = cvtpk(a.z, a.w);
  o.z = cvtpk(b.x, b.y); o.w = cvtpk(b.z, b.w);
  ((uint4*)out)[i] = o;
}

// ---------- 2) transpose + cast: in (R,C) fp32 -> out (C,R) bf16 ----------
__global__ __launch_bounds__(256) void transpose_cast_kernel(
    const float* __restrict__ in, ushort_t* __restrict__ out, int R, int C) {
  __shared__ float tile[32][33];
  int tx = threadIdx.x, ty = threadIdx.y;
  int c0 = blockIdx.x * 32, r0 = blockIdx.y * 32;
#pragma unroll
  for (int i = 0; i < 4; ++i)
    tile[ty + i * 8][tx] = in[(size_t)(r0 + ty + i * 8) * C + c0 + tx];
  __syncthreads();
#pragma unroll
  for (int i = 0; i < 4; ++i)
    out[(size_t)(c0 + ty + i * 8) * R + r0 + tx] = f2bf(tile[tx][ty + i * 8]);
}

// ---------- 3a) legacy GEMM (m97-class): C = A * BT^T, 128^2 tile ----------
template <int OUT_BF16>
__global__ __launch_bounds__(256, 2) void gemm_bt_kernel(
    const ushort_t* __restrict__ A, const ushort_t* __restrict__ BT,
    void* __restrict__ Cout, int M, int N, int K, int nx, int cpx) {
  const int lin = blockIdx.x;
  const int swz = (lin & 7) * cpx + (lin >> 3);
  const int bx = swz % nx, by = swz / nx;

  __shared__ ushort_t As[128 * 32];
  __shared__ ushort_t Bs[128 * 32];
  const int tid = threadIdx.x;
  const int lane = tid & 63;
  const int wid = tid >> 6;
  const int wr = wid >> 1, wc = wid & 1;
  const int qr = lane & 15, kg = lane >> 4;
  const size_t arow = (size_t)by * 128;
  const size_t brow = (size_t)bx * 128;

  f32x4 acc[4][4] = {};

  for (int k0 = 0; k0 < K; k0 += 32) {
    __syncthreads();
#pragma unroll
    for (int t = 0; t < 2; ++t) {
      int c = (t * 4 + wid) * 64 + lane;
      int r = c >> 2, kc = (c & 3) * 8;
      gload_lds16(A + (arow + r) * K + k0 + kc, &As[(t * 4 + wid) * 512]);
      gload_lds16(BT + (brow + r) * K + k0 + kc, &Bs[(t * 4 + wid) * 512]);
    }
    __syncthreads();
    bf16x8 af[4], bfr[4];
#pragma unroll
    for (int m = 0; m < 4; ++m)
      af[m] = *(const bf16x8*)&As[(wr * 64 + m * 16 + qr) * 32 + kg * 8];
#pragma unroll
    for (int n = 0; n < 4; ++n)
      bfr[n] = *(const bf16x8*)&Bs[(wc * 64 + n * 16 + qr) * 32 + kg * 8];
#pragma unroll
    for (int m = 0; m < 4; ++m)
#pragma unroll
      for (int n = 0; n < 4; ++n)
        acc[m][n] = __builtin_amdgcn_mfma_f32_16x16x32_bf16(af[m], bfr[n], acc[m][n], 0, 0, 0);
  }

#pragma unroll
  for (int m = 0; m < 4; ++m)
#pragma unroll
    for (int n = 0; n < 4; ++n)
#pragma unroll
      for (int j = 0; j < 4; ++j) {
        size_t row = arow + wr * 64 + m * 16 + kg * 4 + j;
        size_t col = brow + wc * 64 + n * 16 + qr;
        float v = acc[m][n][j];
        if (OUT_BF16) ((ushort_t*)Cout)[row * N + col] = f2bf(v);
        else ((float*)Cout)[row * N + col] = v;
      }
}

// ---------- 3b) 8-phase 256^2 GEMM (T2+T3+T4+T5), bf16 out ----------
#define G8_BAR() { __builtin_amdgcn_sched_barrier(0); __builtin_amdgcn_s_barrier(); __builtin_amdgcn_sched_barrier(0); }
#define G8_RDA(base, mh) { _Pragma("unroll") for (int mm = 0; mm < 4; ++mm) { const int r_ = (base) + ((mh) * 64 + mm * 16 + qr) * 128; af[mm][0] = *(const bf16x8*)(smem + r_ + kgx0); af[mm][1] = *(const bf16x8*)(smem + r_ + kgx1); } }
#define G8_RDB(base, nh) { _Pragma("unroll") for (int nn = 0; nn < 2; ++nn) { const int r_ = (base) + (rbo + (nh) * 32 + nn * 16 + qr) * 128; bfr[nn][0] = *(const bf16x8*)(smem + r_ + kgx0); bfr[nn][1] = *(const bf16x8*)(smem + r_ + kgx1); } }
#define G8_MFMA(mh, nh) { __builtin_amdgcn_s_setprio(1); _Pragma("unroll") for (int mm = 0; mm < 4; ++mm) _Pragma("unroll") for (int nn = 0; nn < 2; ++nn) { f32x4 a_ = acc[(mh) * 4 + mm][(nh) * 2 + nn]; a_ = __builtin_amdgcn_mfma_f32_16x16x32_bf16(af[mm][0], bfr[nn][0], a_, 0, 0, 0); a_ = __builtin_amdgcn_mfma_f32_16x16x32_bf16(af[mm][1], bfr[nn][1], a_, 0, 0, 0); acc[(mh) * 4 + mm][(nh) * 2 + nn] = a_; } __builtin_amdgcn_s_setprio(0); }

__global__ __launch_bounds__(512, 2) void gemm8_kernel(
    const ushort_t* __restrict__ A, const ushort_t* __restrict__ BT,
    ushort_t* __restrict__ C, int M, int N, int K, int nx, int cpx) {
  __shared__ __align__(16) char smem[131072];
  const int lin = blockIdx.x;
  const int swz = (lin & 7) * cpx + (lin >> 3);
  const int bx = swz % nx, by = swz / nx;
  const int tid = threadIdx.x;
  const int lane = tid & 63;
  const int wid = tid >> 6;
  const int wr = wid >> 2, wc = wid & 3;
  const int qr = lane & 15, kg = lane >> 4;
  const int rbo = (wc & 1) * 64;
  const int kgx0 = (kg << 4) ^ ((qr & 7) << 4);
  const int kgx1 = ((kg | 4) << 4) ^ ((qr & 7) << 4);
  const int ab0 = wr * 16384, ab1 = 65536 + wr * 16384;
  const int bb0 = 32768 + (wc >> 1) * 16384;
  const int bb1 = 65536 + 32768 + (wc >> 1) * 16384;
  const int srow = tid >> 3;
  const int scol = ((tid & 7) ^ (srow & 7)) << 3;

  const ushort_t* Ab = A + (size_t)(by * 256 + srow) * K + scol;
  const ushort_t* Bb = BT + (size_t)(bx * 256 + srow) * K + scol;
  const size_t r64 = (size_t)64 * K;
  const size_t r128 = (size_t)128 * K;

  f32x4 acc[8][4] = {};
  bf16x8 af[4][2], bfr[2][2];

  auto stA = [&](int h, int s, int rb) {
    const ushort_t* p = Ab + (h ? r128 : 0) + s * 64;
    gload_lds16(p, smem + rb + tid * 16);
    gload_lds16(p + r64, smem + rb + 8192 + tid * 16);
  };
  auto stB = [&](int h, int s, int rb) {
    const ushort_t* p = Bb + (h ? r128 : 0) + s * 64;
    gload_lds16(p, smem + rb + tid * 16);
    gload_lds16(p + r64, smem + rb + 8192 + tid * 16);
  };

  // prologue: step 0 -> buf0 (4 half-tiles), step 1 A -> buf1 (2)
  stA(0, 0, 0); stA(1, 0, 16384); stB(0, 0, 32768); stB(1, 0, 49152);
  stA(0, 1, 65536); stA(1, 1, 81920);
  asm volatile("s_waitcnt vmcnt(4)" ::: "memory");
  G8_BAR()

#pragma unroll 1
  for (int it = 0; it < 16; ++it) {
    const int e = it * 2;
    const bool nl = (it < 15);
    G8_RDA(ab0, 0) G8_RDB(bb0, 0)
    stB(0, e + 1, 98304);
    G8_BAR() G8_MFMA(0, 0) G8_BAR()
    G8_RDB(bb0, 1)
    stB(1, e + 1, 114688);
    G8_BAR() G8_MFMA(0, 1) G8_BAR()
    G8_RDA(ab0, 1)
    G8_BAR() G8_MFMA(1, 1) G8_BAR()
    G8_RDB(bb0, 0)
    if (nl) { stA(0, e + 2, 0); stA(1, e + 2, 16384); }
    G8_BAR() G8_MFMA(1, 0)
    if (nl) { asm volatile("s_waitcnt vmcnt(4)" ::: "memory"); }
    else    { asm volatile("s_waitcnt vmcnt(0)" ::: "memory"); }
    G8_BAR()
    G8_RDA(ab1, 0) G8_RDB(bb1, 0)
    if (nl) { stB(0, e + 2, 32768); stB(1, e + 2, 49152); }
    G8_BAR() G8_MFMA(0, 0) G8_BAR()
    G8_RDB(bb1, 1)
    G8_BAR() G8_MFMA(0, 1) G8_BAR()
    G8_RDA(ab1, 1)
    G8_BAR() G8_MFMA(1, 1) G8_BAR()
    G8_RDB(bb1, 0)
    if (nl) { stA(0, e + 3, 65536); stA(1, e + 3, 81920); }
    G8_BAR() G8_MFMA(1, 0)
    asm volatile("s_waitcnt vmcnt(4)" ::: "memory");
    G8_BAR()
  }

#pragma unroll
  for (int m = 0; m < 8; ++m)
#pragma unroll
    for (int n = 0; n < 4; ++n)
#pragma unroll
      for (int j = 0; j < 4; ++j) {
        size_t row = (size_t)by * 256 + wr * 128 + m * 16 + kg * 4 + j;
        size_t col = (size_t)bx * 256 + wc * 64 + n * 16 + qr;
        C[row * N + col] = f2bf(acc[m][n][j]);
      }
}

// ---------- 4) fused Gemma-RMSNorm + RoPE on q/k rows of qkv, in place ----------
// q rows (idx<16) pre-scaled by log2(e)/sqrt(D) = log2e/16 so the attention
// softmax runs in exp2 domain (saves the log2e multiplies per tile).
__global__ __launch_bounds__(256) void normrope_kernel(
    ushort_t* __restrict__ qkv, const int* __restrict__ positions,
    const float* __restrict__ qw, const float* __restrict__ kw) {
  const int wv = blockIdx.x * 4 + (threadIdx.x >> 6);
  const int lane = threadIdx.x & 63;
  const int t = wv / 18;
  const int idx = wv % 18;
  size_t base;
  const float* w;
  float sc;
  if (idx < 16) { base = (size_t)t * 9216 + idx * 512; w = qw; sc = 0.09016844005556021f; }
  else { base = (size_t)t * 9216 + 8192 + (size_t)(idx - 16) * 256; w = kw; sc = 1.0f; }

  ushort4 raw = *(const ushort4*)(qkv + base + lane * 4);
  float x0 = bf2f(raw.x), x1 = bf2f(raw.y), x2 = bf2f(raw.z), x3 = bf2f(raw.w);
  float ss = x0 * x0 + x1 * x1 + x2 * x2 + x3 * x3;
#pragma unroll
  for (int off = 1; off < 64; off <<= 1) ss += __shfl_xor(ss, off);
  float inv = rsqrtf(ss * (1.0f / 256.0f) + 1e-6f);
  const int d0 = lane * 4;
  float xn[4] = { x0 * inv * (1.f + w[d0]), x1 * inv * (1.f + w[d0 + 1]),
                  x2 * inv * (1.f + w[d0 + 2]), x3 * inv * (1.f + w[d0 + 3]) };
  float pn[4];
#pragma unroll
  for (int j = 0; j < 4; ++j) pn[j] = __shfl_xor(xn[j], 8);
  if (lane < 16) {
    const float pos = (float)positions[t];
#pragma unroll
    for (int j = 0; j < 4; ++j) {
      int d = d0 + j;
      int i = d & 31;
      float invf = __expf(-(float)i * 0.28782313662425574f);  // 10000^(-i/32)
      float fr = pos * invf;
      float s, c;
      sincosf(fr, &s, &c);
      xn[j] = (d < 32) ? (xn[j] * c - pn[j] * s) : (xn[j] * c + pn[j] * s);
    }
  }
  ushort4 o = make_ushort4(f2bf(xn[0] * sc), f2bf(xn[1] * sc),
                           f2bf(xn[2] * sc), f2bf(xn[3] * sc));
  *(ushort4*)(qkv + base + lane * 4) = o;
}

// ---------- 4b) V global transpose with interleaved slot order ----------
// VTg[kvh][d][t0 + s] = V[t0 + perm(s)][kvh][d],
// perm(s) = ((s&1)<<4) + ((s>>3)<<2) + ((s&7)>>1)  (verified rounds 5/6/8/10).
__global__ __launch_bounds__(256) void vtranspose_kernel(
    const ushort_t* __restrict__ qkv, ushort_t* __restrict__ VTg) {
  __shared__ ushort_t tile[32][34];
  const int tx = threadIdx.x, ty = threadIdx.y;
  const int t0 = blockIdx.x * 32, d0 = blockIdx.y * 32, kvh = blockIdx.z;
#pragma unroll
  for (int i = 0; i < 4; ++i) {
    int s = ty + i * 8;
    int kvl = ((s & 1) << 4) + ((s >> 3) << 2) + ((s & 7) >> 1);  // perm(s)
    tile[s][tx] = qkv[(size_t)(t0 + kvl) * 9216 + 8704 + kvh * 256 + d0 + tx];
  }
  __syncthreads();
#pragma unroll
  for (int i = 0; i < 4; ++i)
    VTg[(size_t)kvh * 1048576 + (size_t)(d0 + ty + i * 8) * 4096 + t0 + tx] =
        tile[tx][ty + i * 8];
}

// ---------- softmax for one q-group (swapped-QK, exp2 domain) ----------
// Scores arrive pre-scaled by log2e/16 (normrope). p = 2^(v - m); P and l
// share the base so softmax is unchanged. Pack via v_cvt_pk_bf16_f32 (RNE).
__device__ __forceinline__ bf16x8 softmax_group(
    f32x4 sA, f32x4 sB, int kv0, int qg, bool full,
    float& mr, float& lr, f32x4* o, int kg) {
  float v[8];
#pragma unroll
  for (int j = 0; j < 4; ++j) v[j] = sA[j];
#pragma unroll
  for (int j = 0; j < 4; ++j) v[4 + j] = sB[j];
  if (!full) {
#pragma unroll
    for (int j = 0; j < 4; ++j) {
      if (kv0 + kg * 4 + j > qg) v[j] = -1e30f;
      if (kv0 + 16 + kg * 4 + j > qg) v[4 + j] = -1e30f;
    }
  }
  float tm = v[0];
#pragma unroll
  for (int j = 1; j < 8; ++j) tm = fmaxf(tm, v[j]);
  tm = fmaxf(tm, __shfl_xor(tm, 16));
  tm = fmaxf(tm, __shfl_xor(tm, 32));
  float mref;
  if (__all(tm - mr <= 8.0f)) {
    mref = mr;  // defer-max (T13): P bounded by 2^8
  } else {
    float mnew = fmaxf(mr, tm);
    float corr = fexp2(mr - mnew);
    lr *= corr;
    float c0 = __shfl(corr, kg * 4 + 0);
    float c1 = __shfl(corr, kg * 4 + 1);
    float c2 = __shfl(corr, kg * 4 + 2);
    float c3 = __shfl(corr, kg * 4 + 3);
#pragma unroll
    for (int n = 0; n < 16; ++n) {
      o[n][0] *= c0; o[n][1] *= c1; o[n][2] *= c2; o[n][3] *= c3;
    }
    mr = mnew; mref = mnew;
  }
  float p[8];
#pragma unroll
  for (int j = 0; j < 8; ++j) p[j] = fexp2(v[j] - mref);
  float ps = 0.f;
#pragma unroll
  for (int j = 0; j < 8; ++j) ps += p[j];
  ps += __shfl_xor(ps, 16);
  ps += __shfl_xor(ps, 32);
  lr += ps;
  union { u32x4 u; bf16x8 b; } pk;
#pragma unroll
  for (int u2 = 0; u2 < 4; ++u2)
    pk.u[u2] = cvtpk(p[u2], p[4 + u2]);
  return pk.b;
}

// ---------- 5) causal flash attention + sigmoid gate (round-10 structure) ----------
__global__ __launch_bounds__(256, 2) void attn_kernel(
    const ushort_t* __restrict__ qkv, const ushort_t* __restrict__ VTg,
    ushort_t* __restrict__ A2) {
  const int id = blockIdx.x;
  const int g8 = id & 255, kk = id >> 8;
  const int x = g8 >> 4;
  const int h = ((g8 & 1) << 3) | ((g8 >> 1) & 7);
  const int qt = (3 - kk) * 16 + ((kk & 1) ? (15 - x) : x);
  const int kvh = g8 & 1;  // == h>>3
  const int tid = threadIdx.x;
  const int lane = tid & 63;
  const int wid = tid >> 6;
  const int qr = lane & 15, kg = lane >> 4;

  __shared__ __align__(16) ushort_t Ks[2][32 * 256];  // [kv][d], chunk-XOR swz
  __shared__ __align__(16) ushort_t Vt[2][256 * 32];  // [d][slot], chunk-XOR swz

  const int q0 = qt * 64;
  const int myq0 = q0 + wid * 16;
  const ushort_t* vtg = VTg + (size_t)kvh * 1048576;

  bf16x8 qf[8];
#pragma unroll
  for (int kd = 0; kd < 8; ++kd)
    qf[kd] = *(const bf16x8*)(qkv + (size_t)(myq0 + qr) * 9216 + h * 512 +
                              kd * 32 + kg * 8);

  f32x4 o[16] = {};
  float mr = -1e30f, lr = 0.f;

  const int nt = qt * 2 + 2;

  // prologue: issue tile 0 into buf 0
#pragma unroll
  for (int t = 0; t < 4; ++t) {
    int c = (t * 4 + wid) * 64 + lane;
    int r = c >> 5, dc = c & 31;
    int dcs = dc ^ (r & 7);
    gload_lds16(qkv + (size_t)r * 9216 + 8192 + kvh * 256 + dcs * 8,
                &Ks[0][(t * 4 + wid) * 512]);
  }
#pragma unroll
  for (int t = 0; t < 4; ++t) {
    int c = (t * 4 + wid) * 64 + lane;
    int d = c >> 2, k2 = c & 3;
    int kc = k2 ^ ((d >> 1) & 3);  // inverse chunk permutation in source
    gload_lds16(vtg + (size_t)d * 4096 + kc * 8,
                &Vt[0][(t * 4 + wid) * 512]);
  }

  int buf = 0;
  for (int kt = 0; kt < nt; ++kt) {
    const int kv0 = kt * 32;
    __syncthreads();  // tile kt staged (loads aged one full compute phase)

    // ---- issue stage of tile t+1 into the other buffer ----
    if (kt + 1 < nt) {
      const int kv0n = kv0 + 32;
#pragma unroll
      for (int t = 0; t < 4; ++t) {
        int c = (t * 4 + wid) * 64 + lane;
        int r = c >> 5, dc = c & 31;
        int dcs = dc ^ (r & 7);
        gload_lds16(qkv + (size_t)(kv0n + r) * 9216 + 8192 + kvh * 256 + dcs * 8,
                    &Ks[buf ^ 1][(t * 4 + wid) * 512]);
      }
#pragma unroll
      for (int t = 0; t < 4; ++t) {
        int c = (t * 4 + wid) * 64 + lane;
        int d = c >> 2, k2 = c & 3;
        int kc = k2 ^ ((d >> 1) & 3);
        gload_lds16(vtg + (size_t)d * 4096 + kv0n + kc * 8,
                    &Vt[buf ^ 1][(t * 4 + wid) * 512]);
      }
    }
    __builtin_amdgcn_sched_barrier(0);

    // ---- compute tile t ----
    const bool active = (kv0 <= myq0 + 15);  // wave-uniform causal skip
    if (active) {
      const char* ksb = (const char*)&Ks[buf][0];
      const int kxor = (qr & 7) << 4;
      const int kbase = qr * 512;
      f32x4 s0 = {0.f, 0.f, 0.f, 0.f}, s1 = {0.f, 0.f, 0.f, 0.f};
      __builtin_amdgcn_s_setprio(1);
#pragma unroll
      for (int kd = 0; kd < 8; ++kd) {
        int off = kbase + ((kd * 64 + kg * 16) ^ kxor);
        bf16x8 kf0 = *(const bf16x8*)(ksb + off);
        bf16x8 kf1 = *(const bf16x8*)(ksb + off + 8192);
        s0 = __builtin_amdgcn_mfma_f32_16x16x32_bf16(kf0, qf[kd], s0, 0, 0, 0);
        s1 = __builtin_amdgcn_mfma_f32_16x16x32_bf16(kf1, qf[kd], s1, 0, 0, 0);
      }
      __builtin_amdgcn_s_setprio(0);

      const bool full = (kv0 + 31 <= myq0);
      bf16x8 pf = softmax_group(s0, s1, kv0, myq0 + qr, full, mr, lr, o, kg);

      const char* vtb = (const char*)&Vt[buf][0];
      const int vxor = (qr >> 1) & 3;  // read-side chunk permutation
      __builtin_amdgcn_s_setprio(1);
#pragma unroll
      for (int n = 0; n < 16; ++n) {
        int dcol = n * 16 + qr;
        bf16x8 vf = *(const bf16x8*)(vtb + dcol * 64 + ((kg ^ vxor) * 16));
        o[n] = __builtin_amdgcn_mfma_f32_16x16x32_bf16(pf, vf, o[n], 0, 0, 0);
      }
      __builtin_amdgcn_s_setprio(0);
    }
    buf ^= 1;
  }

  // epilogue: 1/l, sigmoid gate, bf16 store
  float rl[4];
#pragma unroll
  for (int j = 0; j < 4; ++j) rl[j] = 1.0f / __shfl(lr, kg * 4 + j);
#pragma unroll
  for (int n = 0; n < 16; ++n) {
    int d = n * 16 + qr;
#pragma unroll
    for (int j = 0; j < 4; ++j) {
      int t = myq0 + kg * 4 + j;
      float val = o[n][j] * rl[j];
      float g2 = bf2f(qkv[(size_t)t * 9216 + h * 512 + 256 + d]);
      val *= 1.0f / (1.0f + __expf(-g2));
      A2[(size_t)t * 4096 + h * 256 + d] = f2bf(val);
    }
  }
}

// ---------- launch ----------
extern "C" void kernel_launch(void* const* d_in, const int* in_sizes, int n_in,
                              void* d_out, int out_size, void* d_ws, size_t ws_size,
                              hipStream_t stream) {
  const float* hidden = (const float*)d_in[0];
  const int* positions = (const int*)d_in[1];
  const float* w_qkv = (const float*)d_in[2];
  const float* w_o = (const float*)d_in[3];
  const float* q_norm_w = (const float*)d_in[4];
  const float* k_norm_w = (const float*)d_in[5];

  char* ws = (char*)d_ws;
  ushort_t* hb    = (ushort_t*)ws;                          // hidden bf16 (dead after GEMM1)
  ushort_t* VTg   = (ushort_t*)ws;                          // aliases hb: V^T (2,256,4096) bf16
  ushort_t* wqkvT = (ushort_t*)(ws + 16777216);             // w_qkv^T bf16 (9216,2048)
  ushort_t* woT   = (ushort_t*)(ws + 54525952);             // w_o^T bf16 (2048,4096)
  ushort_t* qkvb  = (ushort_t*)(ws + 71303168);             // qkv bf16 (4096,9216)
  ushort_t* A2    = (ushort_t*)(ws + 146800640);            // gated attn bf16 (4096,4096)

  hipLaunchKernelGGL(cast_bf16_kernel, dim3(4096), dim3(256), 0, stream,
                     hidden, (uint_t*)hb, 1048576);
  hipLaunchKernelGGL(transpose_cast_kernel, dim3(288, 64), dim3(32, 8), 0, stream,
                     w_qkv, wqkvT, 2048, 9216);
  hipLaunchKernelGGL(transpose_cast_kernel, dim3(64, 128), dim3(32, 8), 0, stream,
                     w_o, woT, 4096, 2048);
  hipLaunchKernelGGL(gemm8_kernel, dim3(576), dim3(512), 0, stream,
                     hb, wqkvT, qkvb, 4096, 9216, 2048, 36, 72);
  hipLaunchKernelGGL(normrope_kernel, dim3(18432), dim3(256), 0, stream,
                     qkvb, positions, q_norm_w, k_norm_w);
  hipLaunchKernelGGL(vtranspose_kernel, dim3(128, 8, 2), dim3(32, 8), 0, stream,
                     qkvb, VTg);
  hipLaunchKernelGGL(attn_kernel, dim3(1024), dim3(256), 0, stream,
                     qkvb, VTg, A2);
  hipLaunchKernelGGL((gemm_bt_kernel<0>), dim3(512), dim3(256), 0, stream,
                     A2, woT, d_out, 4096, 2048, 4096, 16, 64);
}